// Round 4
// baseline (250.309 us; speedup 1.0000x reference)
//
#include <hip/hip_runtime.h>
#include <hip/hip_bf16.h>
#include <math.h>

#define BATCH 2
#define CDIM 128
#define SS 16
#define HH_ 32
#define WW_ 32
#define NSP (SS*HH_*WW_)
#define GS 8
#define GH 16
#define GW 16
#define GN (GS*GH*GW)
#define HEADS 8
#define DH 16
#define NW 256
#define W3L 64
#define W3G 8
#define TOPK 4
#define W3 (W3L + TOPK*W3G)
#define LN_EPS 1e-6f
#define ROUTE_SCALE 0.08838834764831845f
#define GATTN_SCALE 0.25f

typedef short bshort8 __attribute__((ext_vector_type(8)));
typedef float f32x4 __attribute__((ext_vector_type(4)));

__device__ __forceinline__ unsigned short f2bf(float f) {
    unsigned int u = __float_as_uint(f);
    unsigned int r = (u + 0x7fffu + ((u >> 16) & 1u)) >> 16;
    return (unsigned short)r;
}
// branchless erf (A&S 7.1.26, |err| < 1.5e-7 — far below bf16 noise)
__device__ __forceinline__ float gelu_exact(float x) {
    float z = x * 0.70710678118654752f;
    float az = fabsf(z);
    float t = 1.0f / fmaf(0.3275911f, az, 1.0f);
    float poly = t * fmaf(t, fmaf(t, fmaf(t, fmaf(t, 1.061405429f, -1.453152027f),
                     1.421413741f), -0.284496736f), 0.254829592f);
    float e = __expf(-az * az);
    float erfv = 1.0f - poly * e;
    erfv = (z < 0.f) ? -erfv : erfv;
    return 0.5f * x * (1.0f + erfv);
}
__device__ __forceinline__ float shfl_sum32(float v) {
#pragma unroll
    for (int m = 16; m > 0; m >>= 1) v += __shfl_xor(v, m);
    return v;
}
__device__ __forceinline__ float shfl_sum16(float v) {
#pragma unroll
    for (int m = 8; m > 0; m >>= 1) v += __shfl_xor(v, m);
    return v;
}
__device__ __forceinline__ float shfl_sum8(float v) {
#pragma unroll
    for (int m = 4; m > 0; m >>= 1) v += __shfl_xor(v, m);
    return v;
}

// ---------------- K0: weight prep -> FRAGMENT-ORDERED bf16 ----------------
// wf[((tile*KS + ks)*64 + lane)*8 + e] = W_src[(ks*32 + (lane>>4)*8 + e) * OUT + tile*16 + (lane&15)]
__global__ __launch_bounds__(256) void k_wprep_all(const float* __restrict__ gqkv_w,
        const float* __restrict__ m2_w1, const float* __restrict__ m2_w2,
        const float* __restrict__ proj_w, const float* __restrict__ mlp_w1,
        const float* __restrict__ mlp_w2, const float* __restrict__ wo_w,
        const float* __restrict__ qkv_w,
        unsigned short* __restrict__ wt, unsigned short* __restrict__ w1t,
        unsigned short* __restrict__ w2t, unsigned short* __restrict__ projt,
        unsigned short* __restrict__ gw1t, unsigned short* __restrict__ gw2t,
        unsigned short* __restrict__ wot, unsigned short* __restrict__ qkvt) {
    int id = blockIdx.x * 256 + threadIdx.x;   // 0..49151
    int frag = id >> 6, lane = id & 63;
    int l15 = lane & 15, quad = lane >> 4;
    const float* srcw; unsigned short* dstw; int KS, OUT, lf; float sc = 1.f;
    if (frag < 96)        { lf = frag;       srcw = gqkv_w; dstw = wt;    KS = 4;  OUT = 384; if ((lf >> 2) < 8) sc = ROUTE_SCALE; }
    else if (frag < 224)  { lf = frag - 96;  srcw = m2_w1;  dstw = w1t;   KS = 4;  OUT = 512; }
    else if (frag < 352)  { lf = frag - 224; srcw = m2_w2;  dstw = w2t;   KS = 16; OUT = 128; }
    else if (frag < 384)  { lf = frag - 352; srcw = proj_w; dstw = projt; KS = 4;  OUT = 128; }
    else if (frag < 512)  { lf = frag - 384; srcw = mlp_w1; dstw = gw1t;  KS = 4;  OUT = 512; }
    else if (frag < 640)  { lf = frag - 512; srcw = mlp_w2; dstw = gw2t;  KS = 16; OUT = 128; }
    else if (frag < 672)  { lf = frag - 640; srcw = wo_w;   dstw = wot;   KS = 4;  OUT = 128; }
    else                  { lf = frag - 672; srcw = qkv_w;  dstw = qkvt;  KS = 4;  OUT = 384; if ((lf >> 2) < 8) sc = GATTN_SCALE; }
    int ksh = (KS == 16) ? 4 : 2;
    int tile = lf >> ksh, ks = lf & (KS - 1);
    int n = tile * 16 + l15;
    int k0 = ks * 32 + quad * 8;
    const float* s = srcw + (size_t)k0 * OUT + n;
    unsigned short o[8];
#pragma unroll
    for (int e = 0; e < 8; e++) o[e] = f2bf(s[(size_t)e * OUT] * sc);
    unsigned short* d = dstw + ((size_t)lf * 64 + lane) * 8;
    *(ushort4*)d = *(ushort4*)&o[0];
    *(ushort4*)(d + 4) = *(ushort4*)&o[4];
}

// ---------------- K1: global branch qkv via MFMA, 16 tokens/block (256 blocks) ----------------
__global__ __launch_bounds__(256) void k_gqkv_mfma(const float* __restrict__ xg_in,
        const unsigned short* __restrict__ qkvt, const float* __restrict__ qkv_b,
        const float* __restrict__ ln_g, const float* __restrict__ ln_b,
        float* __restrict__ xg, unsigned short* __restrict__ qgb,
        unsigned short* __restrict__ kgb, unsigned short* __restrict__ vgtb) {
    int blk = blockIdx.x; int b = blk >> 7; int n0 = (blk & 127) * 16;
    int t = threadIdx.x; int w = t >> 6; int lane = t & 63;
    int l15 = lane & 15, quad = lane >> 4;
    __shared__ __align__(16) float xs[16 * 132];
    __shared__ __align__(16) unsigned short h[16 * 136];
    f32x4 zero4 = {0.f, 0.f, 0.f, 0.f};

    {   // transpose load: thread t -> channel c, token-octet
        int c = t >> 1, j0 = (t & 1) * 8;
        const float* src = xg_in + ((size_t)(b * 128 + c)) * GN + n0 + j0;
        float4 v0 = *(const float4*)src;
        float4 v1 = *(const float4*)(src + 4);
        xs[(j0 + 0) * 132 + c] = v0.x; xs[(j0 + 1) * 132 + c] = v0.y;
        xs[(j0 + 2) * 132 + c] = v0.z; xs[(j0 + 3) * 132 + c] = v0.w;
        xs[(j0 + 4) * 132 + c] = v1.x; xs[(j0 + 5) * 132 + c] = v1.y;
        xs[(j0 + 6) * 132 + c] = v1.z; xs[(j0 + 7) * 132 + c] = v1.w;
    }
    __syncthreads();
    {   // LN: 16 threads/token, 8 ch each; write xg fp32 + h bf16
        int j = t >> 4, p = t & 15, c0 = p * 8;
        float vv[8]; float s1 = 0.f;
#pragma unroll
        for (int i = 0; i < 8; i++) { vv[i] = xs[j * 132 + c0 + i]; s1 += vv[i]; }
        s1 = shfl_sum16(s1);
        float mu = s1 * (1.0f / 128.0f);
        float s2 = 0.f;
#pragma unroll
        for (int i = 0; i < 8; i++) { float d = vv[i] - mu; s2 += d * d; }
        s2 = shfl_sum16(s2);
        float rs = rsqrtf(s2 * (1.0f / 128.0f) + LN_EPS);
        float* dst = xg + ((size_t)(b * GN) + n0 + j) * 128 + c0;
        *(float4*)dst = *(float4*)&vv[0];
        *(float4*)(dst + 4) = *(float4*)&vv[4];
        unsigned short hb[8];
#pragma unroll
        for (int i4 = 0; i4 < 2; i4++) {
            float4 g4 = *(const float4*)(ln_g + c0 + i4 * 4);
            float4 b4 = *(const float4*)(ln_b + c0 + i4 * 4);
            hb[i4 * 4 + 0] = f2bf((vv[i4 * 4 + 0] - mu) * rs * g4.x + b4.x);
            hb[i4 * 4 + 1] = f2bf((vv[i4 * 4 + 1] - mu) * rs * g4.y + b4.y);
            hb[i4 * 4 + 2] = f2bf((vv[i4 * 4 + 2] - mu) * rs * g4.z + b4.z);
            hb[i4 * 4 + 3] = f2bf((vv[i4 * 4 + 3] - mu) * rs * g4.w + b4.w);
        }
        *(ushort4*)&h[j * 136 + c0] = *(ushort4*)&hb[0];
        *(ushort4*)&h[j * 136 + c0 + 4] = *(ushort4*)&hb[4];
    }
    __syncthreads();

    bshort8 a[4];
#pragma unroll
    for (int ks = 0; ks < 4; ks++)
        a[ks] = *(const bshort8*)(h + l15 * 136 + ks * 32 + quad * 8);
    int bh_base = b * HEADS;
#pragma unroll
    for (int part = 0; part < 2; part++) {
#pragma unroll
        for (int which = 0; which < 2; which++) {
            int nt = 2 * w + which;
            f32x4 acc = zero4;
#pragma unroll
            for (int ks = 0; ks < 4; ks++) {
                bshort8 bfr = *(const bshort8*)(qkvt + (((size_t)(part * 8 + nt) * 4 + ks) * 64 + lane) * 8);
                acc = __builtin_amdgcn_mfma_f32_16x16x32_bf16(a[ks], bfr, acc, 0, 0, 0);
            }
            int ncol = part * 128 + nt * 16;
            float bias = qkv_b[ncol + l15] * (part == 0 ? GATTN_SCALE : 1.f);
            unsigned short* dst = (part == 0) ? qgb : kgb;
#pragma unroll
            for (int r = 0; r < 4; r++)
                dst[((size_t)(bh_base + nt) * GN + n0 + quad * 4 + r) * DH + l15] = f2bf(acc[r] + bias);
        }
    }
#pragma unroll
    for (int which = 0; which < 2; which++) {
        int mtv = 2 * w + which;
        f32x4 acc = zero4;
#pragma unroll
        for (int ks = 0; ks < 4; ks++) {
            bshort8 aw = *(const bshort8*)(qkvt + (((size_t)(16 + mtv) * 4 + ks) * 64 + lane) * 8);
            acc = __builtin_amdgcn_mfma_f32_16x16x32_bf16(aw, a[ks], acc, 0, 0, 0);
        }
#pragma unroll
        for (int r = 0; r < 4; r++) {
            float bias = qkv_b[256 + mtv * 16 + quad * 4 + r];
            vgtb[((size_t)(bh_base + mtv) * DH + quad * 4 + r) * GN + n0 + l15] = f2bf(acc[r] + bias);
        }
    }
}

// ---------------- K2: global attention via MFMA bf16 ----------------
__global__ __launch_bounds__(256) void k_gattn_mfma(const unsigned short* __restrict__ qgb,
        const unsigned short* __restrict__ kgb, const unsigned short* __restrict__ vgtb,
        float* __restrict__ og) {
    int blk = blockIdx.x;
    int bh = blk >> 7; int qt = (blk & 127) << 4;
    int b = bh >> 3, hh = bh & 7;
    int t = threadIdx.x; int w = t >> 6; int lane = t & 63;
    int col = lane & 15, quad = lane >> 4;
    __shared__ __align__(16) unsigned short Pbuf[4 * 16 * 40];
    __shared__ float po[4][64][4];
    __shared__ float pl[4][64][4];

    bshort8 aq = {0, 0, 0, 0, 0, 0, 0, 0};
    if (quad < 2)
        aq = *(const bshort8*)(qgb + ((size_t)bh * GN + qt + col) * DH + quad * 8);

    f32x4 o = {0.f, 0.f, 0.f, 0.f};
    float lsum[4] = {0.f, 0.f, 0.f, 0.f};
    const unsigned short* kb = kgb + (size_t)bh * GN * DH;
    const unsigned short* vb = vgtb + (size_t)bh * DH * GN;
    unsigned short* pb = Pbuf + w * (16 * 40);
    int row0 = quad * 4;
    int kbeg = w * 512;
    for (int kc = kbeg; kc < kbeg + 512; kc += 32) {
        bshort8 bk0 = {0, 0, 0, 0, 0, 0, 0, 0};
        bshort8 bk1 = {0, 0, 0, 0, 0, 0, 0, 0};
        if (quad < 2) {
            bk0 = *(const bshort8*)(kb + (size_t)(kc + col) * DH + quad * 8);
            bk1 = *(const bshort8*)(kb + (size_t)(kc + 16 + col) * DH + quad * 8);
        }
        f32x4 z = {0.f, 0.f, 0.f, 0.f};
        f32x4 s0 = __builtin_amdgcn_mfma_f32_16x16x32_bf16(aq, bk0, z, 0, 0, 0);
        f32x4 s1 = __builtin_amdgcn_mfma_f32_16x16x32_bf16(aq, bk1, z, 0, 0, 0);
        float p0[4], p1[4];
#pragma unroll
        for (int r = 0; r < 4; r++) {
            p0[r] = __expf(s0[r]); p1[r] = __expf(s1[r]);
            lsum[r] += p0[r] + p1[r];
        }
#pragma unroll
        for (int r = 0; r < 4; r++) {
            pb[(row0 + r) * 40 + col] = f2bf(p0[r]);
            pb[(row0 + r) * 40 + 16 + col] = f2bf(p1[r]);
        }
        bshort8 pA = *(const bshort8*)(pb + col * 40 + quad * 8);
        bshort8 bv = *(const bshort8*)(vb + (size_t)col * GN + kc + quad * 8);
        o = __builtin_amdgcn_mfma_f32_16x16x32_bf16(pA, bv, o, 0, 0, 0);
    }
#pragma unroll
    for (int r = 0; r < 4; r++) {
        float v = lsum[r];
        v += __shfl_xor(v, 1); v += __shfl_xor(v, 2);
        v += __shfl_xor(v, 4); v += __shfl_xor(v, 8);
        lsum[r] = v;
    }
#pragma unroll
    for (int r = 0; r < 4; r++) { po[w][lane][r] = o[r]; pl[w][lane][r] = lsum[r]; }
    __syncthreads();
    if (w == 0) {
#pragma unroll
        for (int r = 0; r < 4; r++) {
            float os = po[0][lane][r] + po[1][lane][r] + po[2][lane][r] + po[3][lane][r];
            float ls = pl[0][lane][r] + pl[1][lane][r] + pl[2][lane][r] + pl[3][lane][r];
            og[((size_t)(b * GN) + qt + quad * 4 + r) * 128 + hh * 16 + col] = os / ls;
        }
    }
}

// ---------------- K3: global proj+residual+LN+MLP via MFMA, 16 tokens/block ----------------
__global__ __launch_bounds__(256) void k_gmlp_mfma(const float* __restrict__ og,
        const float* __restrict__ xg,
        const unsigned short* __restrict__ projt, const float* __restrict__ proj_b,
        const float* __restrict__ ln_g, const float* __restrict__ ln_b,
        const unsigned short* __restrict__ gw1t, const float* __restrict__ b1,
        const unsigned short* __restrict__ gw2t, const float* __restrict__ b2,
        float* __restrict__ xg4, float* __restrict__ gout) {
    int blk = blockIdx.x; int b = blk >> 7; int n0g = (blk & 127) * 16;
    int t = threadIdx.x; int w = t >> 6; int lane = t & 63;
    int l15 = lane & 15, quad = lane >> 4;
    __shared__ __align__(16) unsigned short ao[16 * 136];
    __shared__ __align__(16) float xs[16 * 132];
    __shared__ __align__(16) unsigned short h[16 * 136];
    __shared__ __align__(16) unsigned short h1[16 * 520];
    float* of32 = (float*)h1;
    f32x4 zero4 = {0.f, 0.f, 0.f, 0.f};

    {
        int j = t >> 4, p = t & 15, c0 = p * 8;
        size_t base = ((size_t)(b * GN) + n0g + j) * 128 + c0;
        float4 v0 = *(const float4*)(og + base);
        float4 v1 = *(const float4*)(og + base + 4);
        ushort4 u0 = { f2bf(v0.x), f2bf(v0.y), f2bf(v0.z), f2bf(v0.w) };
        ushort4 u1 = { f2bf(v1.x), f2bf(v1.y), f2bf(v1.z), f2bf(v1.w) };
        *(ushort4*)&ao[j * 136 + c0] = u0;
        *(ushort4*)&ao[j * 136 + c0 + 4] = u1;
        *(float4*)&xs[j * 132 + c0] = *(const float4*)(xg + base);
        *(float4*)&xs[j * 132 + c0 + 4] = *(const float4*)(xg + base + 4);
    }
    __syncthreads();

    {
        bshort8 a[4];
#pragma unroll
        for (int ks = 0; ks < 4; ks++)
            a[ks] = *(const bshort8*)(ao + l15 * 136 + ks * 32 + quad * 8);
#pragma unroll
        for (int nt = 0; nt < 2; nt++) {
            f32x4 acc = zero4;
#pragma unroll
            for (int ks = 0; ks < 4; ks++) {
                bshort8 bfr = *(const bshort8*)(projt + (((size_t)(w * 2 + nt) * 4 + ks) * 64 + lane) * 8);
                acc = __builtin_amdgcn_mfma_f32_16x16x32_bf16(a[ks], bfr, acc, 0, 0, 0);
            }
            int n0 = w * 32 + nt * 16;
            float bias = proj_b[n0 + l15];
#pragma unroll
            for (int r = 0; r < 4; r++) {
                int m = quad * 4 + r;
                xs[m * 132 + n0 + l15] += acc[r] + bias;
            }
        }
    }
    __syncthreads();

    {
        int j = t >> 4, p = t & 15, c0 = p * 8;
        float vv[8]; float s1 = 0.f;
#pragma unroll
        for (int i = 0; i < 8; i++) { vv[i] = xs[j * 132 + c0 + i]; s1 += vv[i]; }
        s1 = shfl_sum16(s1);
        float mu = s1 * (1.0f / 128.0f);
        float s2 = 0.f;
#pragma unroll
        for (int i = 0; i < 8; i++) { float d = vv[i] - mu; s2 += d * d; }
        s2 = shfl_sum16(s2);
        float rs = rsqrtf(s2 * (1.0f / 128.0f) + LN_EPS);
        unsigned short hb[8];
#pragma unroll
        for (int i4 = 0; i4 < 2; i4++) {
            float4 g4 = *(const float4*)(ln_g + c0 + i4 * 4);
            float4 b4 = *(const float4*)(ln_b + c0 + i4 * 4);
            hb[i4 * 4 + 0] = f2bf((vv[i4 * 4 + 0] - mu) * rs * g4.x + b4.x);
            hb[i4 * 4 + 1] = f2bf((vv[i4 * 4 + 1] - mu) * rs * g4.y + b4.y);
            hb[i4 * 4 + 2] = f2bf((vv[i4 * 4 + 2] - mu) * rs * g4.z + b4.z);
            hb[i4 * 4 + 3] = f2bf((vv[i4 * 4 + 3] - mu) * rs * g4.w + b4.w);
        }
        *(ushort4*)&h[j * 136 + c0] = *(ushort4*)&hb[0];
        *(ushort4*)&h[j * 136 + c0 + 4] = *(ushort4*)&hb[4];
    }
    __syncthreads();

    {
        bshort8 a[4];
#pragma unroll
        for (int ks = 0; ks < 4; ks++)
            a[ks] = *(const bshort8*)(h + l15 * 136 + ks * 32 + quad * 8);
#pragma unroll
        for (int nt = 0; nt < 8; nt++) {
            f32x4 acc = zero4;
#pragma unroll
            for (int ks = 0; ks < 4; ks++) {
                bshort8 bfr = *(const bshort8*)(gw1t + (((size_t)(w * 8 + nt) * 4 + ks) * 64 + lane) * 8);
                acc = __builtin_amdgcn_mfma_f32_16x16x32_bf16(a[ks], bfr, acc, 0, 0, 0);
            }
            int n0 = w * 128 + nt * 16;
            float bias = b1[n0 + l15];
#pragma unroll
            for (int r = 0; r < 4; r++)
                h1[(quad * 4 + r) * 520 + n0 + l15] = f2bf(gelu_exact(acc[r] + bias));
        }
    }
    __syncthreads();

    f32x4 acc2[2]; acc2[0] = zero4; acc2[1] = zero4;
#pragma unroll 4
    for (int ks = 0; ks < 16; ks++) {
        bshort8 a = *(const bshort8*)(h1 + l15 * 520 + ks * 32 + quad * 8);
#pragma unroll
        for (int nt = 0; nt < 2; nt++) {
            bshort8 bfr = *(const bshort8*)(gw2t + (((size_t)(w * 2 + nt) * 16 + ks) * 64 + lane) * 8);
            acc2[nt] = __builtin_amdgcn_mfma_f32_16x16x32_bf16(a, bfr, acc2[nt], 0, 0, 0);
        }
    }
    __syncthreads();

    {
#pragma unroll
        for (int nt = 0; nt < 2; nt++) {
            int n0 = w * 32 + nt * 16;
            float bias = b2[n0 + l15];
#pragma unroll
            for (int r = 0; r < 4; r++) {
                int m = quad * 4 + r;
                float ov = xs[m * 132 + n0 + l15] + acc2[nt][r] + bias;
                of32[m * 132 + n0 + l15] = ov;
                xg4[((size_t)(b * GN) + n0g + m) * 128 + n0 + l15] = ov;
            }
        }
    }
    __syncthreads();

    {
        int cw = t >> 1, hf = t & 1, j0 = hf * 8;
        float* dst = gout + ((size_t)(b * 128 + cw)) * GN + n0g + j0;
#pragma unroll
        for (int i4 = 0; i4 < 2; i4++) {
            float4 ov = { of32[(j0 + i4 * 4 + 0) * 132 + cw], of32[(j0 + i4 * 4 + 1) * 132 + cw],
                          of32[(j0 + i4 * 4 + 2) * 132 + cw], of32[(j0 + i4 * 4 + 3) * 132 + cw] };
            *(float4*)(dst + i4 * 4) = ov;
        }
    }
}

// ---------------- K4a: routing q/k ----------------
__global__ void k_routing_qk(const float* __restrict__ xg4,
                             const float* __restrict__ rq_w, const float* __restrict__ rq_b,
                             const float* __restrict__ rk_w, const float* __restrict__ rk_b,
                             float* __restrict__ qh, float* __restrict__ kh) {
    int wid = blockIdx.x; int b = wid / NW, n = wid % NW;
    int c = threadIdx.x;
    int i1 = n / 64, i2 = (n / 8) % 8, i3 = n % 8;
    __shared__ float g[CDIM];
    float s = 0.f;
#pragma unroll
    for (int j = 0; j < W3G; j++) {
        int ds = j >> 2, dh = (j >> 1) & 1, dw = j & 1;
        int gi = ((i1 * 2 + ds) * GH + (i2 * 2 + dh)) * GW + (i3 * 2 + dw);
        s += xg4[((size_t)(b * GN + gi)) * CDIM + c];
    }
    g[c] = s * (1.0f / W3G);
    __syncthreads();
    float aq = rq_b[c], ak = rk_b[c];
    for (int k = 0; k < CDIM; k++) { float gv = g[k]; aq = fmaf(gv, rq_w[k * CDIM + c], aq); ak = fmaf(gv, rk_w[k * CDIM + c], ak); }
    qh[(size_t)wid * CDIM + c] = aq;
    kh[(size_t)wid * CDIM + c] = ak;
}

// ---------------- K4b: top-k ----------------
__global__ void k_topk(const float* __restrict__ qh, const float* __restrict__ kh,
                       int* __restrict__ tidx) {
    int wid = blockIdx.x; int b = wid / NW;
    int m = threadIdx.x;
    __shared__ float q[CDIM];
    __shared__ float lv[NW];
    __shared__ int li[NW];
    if (m < CDIM) q[m] = qh[(size_t)wid * CDIM + m] * ROUTE_SCALE;
    __syncthreads();
    float acc = 0.f;
    const float* kr = kh + ((size_t)b * NW + m) * CDIM;
    for (int k = 0; k < CDIM; k++) acc = fmaf(q[k], kr[k], acc);
#pragma unroll
    for (int sel = 0; sel < TOPK; sel++) {
        lv[m] = acc; li[m] = m; __syncthreads();
#pragma unroll
        for (int s = 128; s > 0; s >>= 1) {
            if (m < s) {
                if (lv[m + s] > lv[m] || (lv[m + s] == lv[m] && li[m + s] < li[m])) {
                    lv[m] = lv[m + s]; li[m] = li[m + s];
                }
            }
            __syncthreads();
        }
        int best = li[0]; __syncthreads();
        if (m == best) acc = -1e30f;
        if (m == 0) tidx[wid * TOPK + sel] = best;
    }
}

// ---------------- K5a: LN local tokens -> lnsc bf16 ----------------
__global__ __launch_bounds__(256) void k_lnsc_local(const float* __restrict__ x_in,
        const float* __restrict__ ln_g, const float* __restrict__ ln_b,
        unsigned short* __restrict__ lnsc) {
    int blk = blockIdx.x;
    int wt = blk & 1; int hh = (blk >> 1) & 31; int s = (blk >> 6) & 15; int b = blk >> 10;
    int w0 = wt * 16;
    int t = threadIdx.x;
    __shared__ float tile[16][132];
    {
        int c = t >> 1; int wq = (t & 1) * 8;
        const float* src = x_in + (((size_t)(b * 128 + c) * SS + s)) * 1024 + hh * 32 + w0 + wq;
        float4 v0 = *(const float4*)src;
        float4 v1 = *(const float4*)(src + 4);
        tile[wq + 0][c] = v0.x; tile[wq + 1][c] = v0.y; tile[wq + 2][c] = v0.z; tile[wq + 3][c] = v0.w;
        tile[wq + 4][c] = v1.x; tile[wq + 5][c] = v1.y; tile[wq + 6][c] = v1.z; tile[wq + 7][c] = v1.w;
    }
    __syncthreads();
    int w = t >> 4; int j = t & 15;
    float vals[8];
    float s1 = 0.f;
#pragma unroll
    for (int i = 0; i < 8; i++) { vals[i] = tile[w][j * 8 + i]; s1 += vals[i]; }
    s1 = shfl_sum16(s1);
    float mu = s1 * (1.0f / 128.0f);
    float s2 = 0.f;
#pragma unroll
    for (int i = 0; i < 8; i++) { float d = vals[i] - mu; s2 += d * d; }
    s2 = shfl_sum16(s2);
    float rs = rsqrtf(s2 * (1.0f / 128.0f) + LN_EPS);
    float4 g0 = *(const float4*)(ln_g + j * 8);
    float4 g1 = *(const float4*)(ln_g + j * 8 + 4);
    float4 b0 = *(const float4*)(ln_b + j * 8);
    float4 b1 = *(const float4*)(ln_b + j * 8 + 4);
    float gv[8] = { g0.x, g0.y, g0.z, g0.w, g1.x, g1.y, g1.z, g1.w };
    float bv[8] = { b0.x, b0.y, b0.z, b0.w, b1.x, b1.y, b1.z, b1.w };
    int ww = w0 + w;
    int n = (s >> 2) * 64 + (hh >> 2) * 8 + (ww >> 2);
    int slot = (s & 3) * 16 + (hh & 3) * 4 + (ww & 3);
    unsigned short* dst = lnsc + ((size_t)(b * NW + n) * W3 + slot) * 128 + j * 8;
    ushort4 u0, u1;
    u0.x = f2bf((vals[0] - mu) * rs * gv[0] + bv[0]);
    u0.y = f2bf((vals[1] - mu) * rs * gv[1] + bv[1]);
    u0.z = f2bf((vals[2] - mu) * rs * gv[2] + bv[2]);
    u0.w = f2bf((vals[3] - mu) * rs * gv[3] + bv[3]);
    u1.x = f2bf((vals[4] - mu) * rs * gv[4] + bv[4]);
    u1.y = f2bf((vals[5] - mu) * rs * gv[5] + bv[5]);
    u1.z = f2bf((vals[6] - mu) * rs * gv[6] + bv[6]);
    u1.w = f2bf((vals[7] - mu) * rs * gv[7] + bv[7]);
    *(ushort4*)dst = u0;
    *(ushort4*)(dst + 4) = u1;
}

// ---------------- K5b: LN gathered global tokens -> lnsc bf16 ----------------
__global__ __launch_bounds__(256) void k_lnsc_gath(const float* __restrict__ xg4,
        const int* __restrict__ tidx,
        const float* __restrict__ ln_g, const float* __restrict__ ln_b,
        unsigned short* __restrict__ lnsc) {
    int blk = blockIdx.x;
    int kk = blk & 3; int wn = blk >> 2;
    int b = wn >> 8;
    int g = tidx[wn * TOPK + kk];
    int gi1 = g >> 6, gi2 = (g >> 3) & 7, gi3 = g & 7;
    int t = threadIdx.x; int j = t >> 5, lj = t & 31;
    int ds = j >> 2, dh = (j >> 1) & 1, dw = j & 1;
    int gi = ((gi1 * 2 + ds) * GH + (gi2 * 2 + dh)) * GW + (gi3 * 2 + dw);
    float4 v = *(const float4*)(xg4 + ((size_t)(b * GN + gi)) * 128 + lj * 4);
    float s1 = shfl_sum32(v.x + v.y + v.z + v.w);
    float mu = s1 * (1.0f / 128.0f);
    float d0 = v.x - mu, d1 = v.y - mu, d2 = v.z - mu, d3 = v.w - mu;
    float s2 = shfl_sum32(d0 * d0 + d1 * d1 + d2 * d2 + d3 * d3);
    float rs = rsqrtf(s2 * (1.0f / 128.0f) + LN_EPS);
    float4 g4 = *(const float4*)(ln_g + lj * 4);
    float4 b4 = *(const float4*)(ln_b + lj * 4);
    ushort4 u;
    u.x = f2bf(d0 * rs * g4.x + b4.x);
    u.y = f2bf(d1 * rs * g4.y + b4.y);
    u.z = f2bf(d2 * rs * g4.z + b4.z);
    u.w = f2bf(d3 * rs * g4.w + b4.w);
    *(ushort4*)(lnsc + ((size_t)wn * W3 + 64 + kk * 8 + j) * 128 + lj * 4) = u;
}

// ---------------- K6: FUSED local attention + wo projection + shortcut ----------------
// 8 waves, one barrier. Wave w: projection ch-slice w -> attention head w -> O (bf16)
// overwrites its OWN Q columns in LDS (Os aliases Qs; same col slice, no hazard).
// After the single barrier: 8-wave wo GEMM reads full O rows, adds x_in shortcut
// (T14-prefetched into regs at kernel entry; staged to xs LDS aliased over dead
// Ks2/Vts -- each wave stages exactly its own channel slice, so no 2nd barrier),
// writes lpre directly. aout buffer + k_wo launch eliminated.
__global__ __launch_bounds__(512, 4) void k_local_wo_mfma(const unsigned short* __restrict__ lnsc,
        const unsigned short* __restrict__ wt, const float* __restrict__ gqkv_b,
        const unsigned short* __restrict__ wot, const float* __restrict__ wo_b,
        const float* __restrict__ x_in, float* __restrict__ lpre) {
    int wn = blockIdx.x;
    int b = wn >> 8; int n = wn & 255;
    int i1 = n >> 6, i2 = (n >> 3) & 7, i3 = n & 7;
    int s0 = i1 * 4, h0 = i2 * 4, w0 = i3 * 4;
    int t = threadIdx.x; int w = t >> 6; int lane = t & 63;
    int l15 = lane & 15, quad = lane >> 4;
    // one buffer, carved: Qs[64*136] | Ks2[96*136] | Vts[128*104] | Ps[8*640]
    __shared__ __align__(16) unsigned short SMEM[64 * 136 + 96 * 136 + 128 * 104 + 8 * 640];
    unsigned short* Qs  = SMEM;                       // aliased by Os (per-wave col slice)
    unsigned short* Ks2 = SMEM + 64 * 136;
    unsigned short* Vts = SMEM + 64 * 136 + 96 * 136;
    unsigned short* Ps  = SMEM + 64 * 136 + 96 * 136 + 128 * 104;
    float* xs = (float*)Ks2;                          // 64*132 f32 spans dead Ks2+Vts

    const unsigned short* Xb = lnsc + (size_t)wn * W3 * 128;
    f32x4 zero4 = {0.f, 0.f, 0.f, 0.f};

    // T14: prefetch shortcut x_in into regs now; LDS-staged after the barrier.
    // thread t: channel cx = t>>2 (wave-local slice), 4 cube-rows of 4 tokens.
    int cx = t >> 2, sub = t & 3;
    float4 xr[4];
#pragma unroll
    for (int i = 0; i < 4; i++) {
        int jr = sub * 4 + i;
        int ds = jr >> 2, dh = jr & 3;
        xr[i] = *(const float4*)(x_in + ((size_t)(b * 128 + cx)) * 16384
                                 + (size_t)(s0 + ds) * 1024 + (h0 + dh) * 32 + w0);
    }

    bshort8 qw[4], kw[4], vw[4];
#pragma unroll
    for (int ks = 0; ks < 4; ks++) {
        qw[ks] = *(const bshort8*)(wt + (((size_t)(0 + w) * 4 + ks) * 64 + lane) * 8);
        kw[ks] = *(const bshort8*)(wt + (((size_t)(8 + w) * 4 + ks) * 64 + lane) * 8);
        vw[ks] = *(const bshort8*)(wt + (((size_t)(16 + w) * 4 + ks) * 64 + lane) * 8);
    }
    float qbias = gqkv_b[w * 16 + l15] * ROUTE_SCALE;
    float kbias = gqkv_b[128 + w * 16 + l15];
    float vbias[4];
#pragma unroll
    for (int r = 0; r < 4; r++) vbias[r] = gqkv_b[256 + w * 16 + quad * 4 + r];

    // ---- projection: wave w computes ch-slice w*16.. of Q,K,V^T ----
    for (int mt = 0; mt < 6; mt++) {
        bshort8 a[4];
#pragma unroll
        for (int ks = 0; ks < 4; ks++)
            a[ks] = *(const bshort8*)(Xb + (mt * 16 + l15) * 128 + ks * 32 + quad * 8);
        f32x4 acck = zero4;
        f32x4 accv = zero4;
#pragma unroll
        for (int ks = 0; ks < 4; ks++) {
            acck = __builtin_amdgcn_mfma_f32_16x16x32_bf16(a[ks], kw[ks], acck, 0, 0, 0);
            accv = __builtin_amdgcn_mfma_f32_16x16x32_bf16(vw[ks], a[ks], accv, 0, 0, 0);
        }
#pragma unroll
        for (int r = 0; r < 4; r++) {
            Ks2[(mt * 16 + quad * 4 + r) * 136 + w * 16 + l15] = f2bf(acck[r] + kbias);
            Vts[(w * 16 + quad * 4 + r) * 104 + mt * 16 + l15] = f2bf(accv[r] + vbias[r]);
        }
        if (mt < 4) {
            f32x4 accq = zero4;
#pragma unroll
            for (int ks = 0; ks < 4; ks++)
                accq = __builtin_amdgcn_mfma_f32_16x16x32_bf16(a[ks], qw[ks], accq, 0, 0, 0);
#pragma unroll
            for (int r = 0; r < 4; r++)
                Qs[(mt * 16 + quad * 4 + r) * 136 + w * 16 + l15] = f2bf(accq[r] + qbias);
        }
    }
    // no barrier: wave w's attention reads only its own LDS column slices.

    // ---- attention: head h = w; O (bf16, /rsum) overwrites own Q columns ----
    unsigned short* Pw = Ps + w * 640;
    bshort8 zfrag = {0, 0, 0, 0, 0, 0, 0, 0};
    int h = w;
    for (int mt = 0; mt < 4; mt++) {
        bshort8 aq = zfrag;
        if (quad < 2)
            aq = *(const bshort8*)(Qs + (mt * 16 + l15) * 136 + h * 16 + quad * 8);
        float rsum[4] = {0.f, 0.f, 0.f, 0.f};
        f32x4 oacc = zero4;
#pragma unroll
        for (int kc = 0; kc < 96; kc += 32) {
#pragma unroll
            for (int sub2 = 0; sub2 < 2; sub2++) {
                int nt = (kc >> 4) + sub2;
                bshort8 bk = zfrag;
                if (quad < 2)
                    bk = *(const bshort8*)(Ks2 + (nt * 16 + l15) * 136 + h * 16 + quad * 8);
                f32x4 s = __builtin_amdgcn_mfma_f32_16x16x32_bf16(aq, bk, zero4, 0, 0, 0);
#pragma unroll
                for (int r = 0; r < 4; r++) {
                    float p = __expf(s[r]);
                    rsum[r] += p;
                    Pw[(quad * 4 + r) * 40 + sub2 * 16 + l15] = f2bf(p);
                }
            }
            bshort8 ap = *(const bshort8*)(Pw + l15 * 40 + quad * 8);
            bshort8 bv = *(const bshort8*)(Vts + (h * 16 + l15) * 104 + kc + quad * 8);
            oacc = __builtin_amdgcn_mfma_f32_16x16x32_bf16(ap, bv, oacc, 0, 0, 0);
        }
#pragma unroll
        for (int r = 0; r < 4; r++) {
            float v = rsum[r];
            v += __shfl_xor(v, 1); v += __shfl_xor(v, 2);
            v += __shfl_xor(v, 4); v += __shfl_xor(v, 8);
            rsum[r] = v;
        }
        // write O into own Q columns (aq for this mt already consumed)
#pragma unroll
        for (int r = 0; r < 4; r++)
            Qs[(mt * 16 + quad * 4 + r) * 136 + h * 16 + l15] = f2bf(oacc[r] / rsum[r]);
    }

    __syncthreads();   // all O written; Ks2/Vts dead -> xs alias safe

    // stage shortcut regs -> xs (wave-local channel slice; read only by same wave)
#pragma unroll
    for (int i = 0; i < 4; i++) {
        int jr = sub * 4 + i;
        xs[(jr * 4 + 0) * 132 + cx] = xr[i].x;
        xs[(jr * 4 + 1) * 132 + cx] = xr[i].y;
        xs[(jr * 4 + 2) * 132 + cx] = xr[i].z;
        xs[(jr * 4 + 3) * 132 + cx] = xr[i].w;
    }

    // ---- wo GEMM: wave w computes output cols w*16.. for all 64 tokens ----
    float wbias = wo_b[w * 16 + l15];
    bshort8 wow[4];
#pragma unroll
    for (int ks = 0; ks < 4; ks++)
        wow[ks] = *(const bshort8*)(wot + (((size_t)w * 4 + ks) * 64 + lane) * 8);
#pragma unroll
    for (int mt = 0; mt < 4; mt++) {
        bshort8 a[4];
#pragma unroll
        for (int ks = 0; ks < 4; ks++)
            a[ks] = *(const bshort8*)(Qs + (mt * 16 + l15) * 136 + ks * 32 + quad * 8);
        f32x4 acc = zero4;
#pragma unroll
        for (int ks = 0; ks < 4; ks++)
            acc = __builtin_amdgcn_mfma_f32_16x16x32_bf16(a[ks], wow[ks], acc, 0, 0, 0);
#pragma unroll
        for (int r = 0; r < 4; r++) {
            int slot = mt * 16 + quad * 4 + r;
            int ds = slot >> 4, dh = (slot >> 2) & 3, dw = slot & 3;
            int sp = (s0 + ds) * 1024 + (h0 + dh) * 32 + (w0 + dw);
            lpre[((size_t)(b * 16384) + sp) * 128 + w * 16 + l15]
                = acc[r] + wbias + xs[slot * 132 + w * 16 + l15];
        }
    }
}

// ---------------- K8: LN + MLP2 via MFMA, 32 tokens/block ----------------
__global__ __launch_bounds__(256) void k_mlp2_mfma(const float* __restrict__ lpre,
        const float* __restrict__ ln_g, const float* __restrict__ ln_b,
        const unsigned short* __restrict__ w1t, const float* __restrict__ b1,
        const unsigned short* __restrict__ w2t, const float* __restrict__ b2,
        float* __restrict__ lout) {
    int blk = blockIdx.x;
    int T0 = blk * 32;
    int b = T0 >> 14;
    int sp = T0 & 16383;
    int t = threadIdx.x; int w = t >> 6; int lane = t & 63;
    int l15 = lane & 15, quad = lane >> 4;
    __shared__ __align__(16) unsigned short buf[32 * 520];
    float* of32 = (float*)buf;

    // T14: issue residual loads NOW; consumed after w2 GEMM (latency hidden).
    float res[2][2][4];
#pragma unroll
    for (int mt = 0; mt < 2; mt++)
#pragma unroll
        for (int nt = 0; nt < 2; nt++)
#pragma unroll
            for (int r = 0; r < 4; r++)
                res[mt][nt][r] = lpre[((size_t)T0 + mt * 16 + quad * 4 + r) * 128 + w * 32 + nt * 16 + l15];

    {
        int j = t >> 3, p = t & 7, c0 = p * 16;
        const float* src = lpre + ((size_t)T0 + j) * 128 + c0;
        float4 v0 = *(const float4*)(src + 0);
        float4 v1 = *(const float4*)(src + 4);
        float4 v2 = *(const float4*)(src + 8);
        float4 v3 = *(const float4*)(src + 12);
        float s1 = (v0.x + v0.y + v0.z + v0.w) + (v1.x + v1.y + v1.z + v1.w)
                 + (v2.x + v2.y + v2.z + v2.w) + (v3.x + v3.y + v3.z + v3.w);
        s1 = shfl_sum8(s1);
        float mu = s1 * (1.0f / 128.0f);
        float vv[16] = { v0.x, v0.y, v0.z, v0.w, v1.x, v1.y, v1.z, v1.w,
                         v2.x, v2.y, v2.z, v2.w, v3.x, v3.y, v3.z, v3.w };
        float s2 = 0.f;
#pragma unroll
        for (int i = 0; i < 16; i++) { float d = vv[i] - mu; s2 += d * d; }
        s2 = shfl_sum8(s2);
        float rs = rsqrtf(s2 * (1.0f / 128.0f) + LN_EPS);
        unsigned short hb[16];
#pragma unroll
        for (int i4 = 0; i4 < 4; i4++) {
            float4 g4 = *(const float4*)(ln_g + c0 + i4 * 4);
            float4 b4 = *(const float4*)(ln_b + c0 + i4 * 4);
            hb[i4 * 4 + 0] = f2bf((vv[i4 * 4 + 0] - mu) * rs * g4.x + b4.x);
            hb[i4 * 4 + 1] = f2bf((vv[i4 * 4 + 1] - mu) * rs * g4.y + b4.y);
            hb[i4 * 4 + 2] = f2bf((vv[i4 * 4 + 2] - mu) * rs * g4.z + b4.z);
            hb[i4 * 4 + 3] = f2bf((vv[i4 * 4 + 3] - mu) * rs * g4.w + b4.w);
        }
        *(ushort4*)&buf[j * 136 + c0 + 0] = *(ushort4*)&hb[0];
        *(ushort4*)&buf[j * 136 + c0 + 4] = *(ushort4*)&hb[4];
        *(ushort4*)&buf[j * 136 + c0 + 8] = *(ushort4*)&hb[8];
        *(ushort4*)&buf[j * 136 + c0 + 12] = *(ushort4*)&hb[12];
    }
    __syncthreads();

    bshort8 a1[2][4];
#pragma unroll
    for (int mt = 0; mt < 2; mt++)
#pragma unroll
        for (int ks = 0; ks < 4; ks++)
            a1[mt][ks] = *(const bshort8*)(buf + (mt * 16 + l15) * 136 + ks * 32 + quad * 8);
    __syncthreads();

    f32x4 zero4 = {0.f, 0.f, 0.f, 0.f};
    {
#pragma unroll
        for (int nt = 0; nt < 8; nt++) {
            int n0 = w * 128 + nt * 16;
            f32x4 acc0 = zero4, acc1 = zero4;
#pragma unroll
            for (int ks = 0; ks < 4; ks++) {
                bshort8 bfr = *(const bshort8*)(w1t + (((size_t)(w * 8 + nt) * 4 + ks) * 64 + lane) * 8);
                acc0 = __builtin_amdgcn_mfma_f32_16x16x32_bf16(a1[0][ks], bfr, acc0, 0, 0, 0);
                acc1 = __builtin_amdgcn_mfma_f32_16x16x32_bf16(a1[1][ks], bfr, acc1, 0, 0, 0);
            }
            float bias = b1[n0 + l15];
#pragma unroll
            for (int r = 0; r < 4; r++) {
                buf[(quad * 4 + r) * 520 + n0 + l15] = f2bf(gelu_exact(acc0[r] + bias));
                buf[(16 + quad * 4 + r) * 520 + n0 + l15] = f2bf(gelu_exact(acc1[r] + bias));
            }
        }
    }
    __syncthreads();

    f32x4 acc[2][2];
    acc[0][0] = zero4; acc[0][1] = zero4; acc[1][0] = zero4; acc[1][1] = zero4;
    {
#pragma unroll 4
        for (int ks = 0; ks < 16; ks++) {
            bshort8 a0 = *(const bshort8*)(buf + (l15) * 520 + ks * 32 + quad * 8);
            bshort8 a1b = *(const bshort8*)(buf + (16 + l15) * 520 + ks * 32 + quad * 8);
#pragma unroll
            for (int nt = 0; nt < 2; nt++) {
                bshort8 bfr = *(const bshort8*)(w2t + (((size_t)(w * 2 + nt) * 16 + ks) * 64 + lane) * 8);
                acc[0][nt] = __builtin_amdgcn_mfma_f32_16x16x32_bf16(a0, bfr, acc[0][nt], 0, 0, 0);
                acc[1][nt] = __builtin_amdgcn_mfma_f32_16x16x32_bf16(a1b, bfr, acc[1][nt], 0, 0, 0);
            }
        }
    }
    __syncthreads();

#pragma unroll
    for (int mt = 0; mt < 2; mt++) {
#pragma unroll
        for (int nt = 0; nt < 2; nt++) {
            int n0 = w * 32 + nt * 16;
            float bias = b2[n0 + l15];
#pragma unroll
            for (int r = 0; r < 4; r++) {
                int m = mt * 16 + quad * 4 + r;
                of32[m * 132 + n0 + l15] = res[mt][nt][r] + acc[mt][nt][r] + bias;
            }
        }
    }
    __syncthreads();

    {
        int c = t >> 1, half = t & 1, j0 = half * 16;
        float* dst = lout + ((size_t)(b * 128 + c)) * NSP + sp + j0;
#pragma unroll
        for (int i4 = 0; i4 < 4; i4++) {
            float4 ov = { of32[(j0 + i4 * 4 + 0) * 132 + c], of32[(j0 + i4 * 4 + 1) * 132 + c],
                          of32[(j0 + i4 * 4 + 2) * 132 + c], of32[(j0 + i4 * 4 + 3) * 132 + c] };
            *(float4*)(dst + i4 * 4) = ov;
        }
    }
}

extern "C" void kernel_launch(void* const* d_in, const int* in_sizes, int n_in,
                              void* d_out, int out_size, void* d_ws, size_t ws_size,
                              hipStream_t stream) {
    const float* x_in   = (const float*)d_in[0];
    const float* xg_in  = (const float*)d_in[1];
    const float* qkv_w  = (const float*)d_in[2];
    const float* qkv_b  = (const float*)d_in[3];
    const float* proj_w = (const float*)d_in[4];
    const float* proj_b = (const float*)d_in[5];
    const float* ln_g   = (const float*)d_in[6];
    const float* ln_b   = (const float*)d_in[7];
    const float* mlp_w1 = (const float*)d_in[8];
    const float* mlp_b1 = (const float*)d_in[9];
    const float* mlp_w2 = (const float*)d_in[10];
    const float* mlp_b2 = (const float*)d_in[11];
    const float* rq_w   = (const float*)d_in[12];
    const float* rq_b   = (const float*)d_in[13];
    const float* rk_w   = (const float*)d_in[14];
    const float* rk_b   = (const float*)d_in[15];
    const float* gqkv_w = (const float*)d_in[16];
    const float* gqkv_b = (const float*)d_in[17];
    const float* wo_w   = (const float*)d_in[18];
    const float* wo_b   = (const float*)d_in[19];
    const float* m2_w1  = (const float*)d_in[20];
    const float* m2_b1  = (const float*)d_in[21];
    const float* m2_w2  = (const float*)d_in[22];
    const float* m2_b2  = (const float*)d_in[23];

    float* out = (float*)d_out;
    float* ws  = (float*)d_ws;

    float* xg4 = ws;                                         // 524288
    float* xg  = ws + 524288;                                // 524288
    unsigned short* qgb  = (unsigned short*)(ws + 1048576);  // 524288 bf16
    unsigned short* kgb  = (unsigned short*)(ws + 1310720);  // 524288 bf16
    unsigned short* vgtb = (unsigned short*)(ws + 1572864);  // 524288 bf16 (V^T)
    float* og  = ws + 1835008;                               // 524288
    float* qh  = ws + 2359296;                               // 65536
    float* kh  = ws + 2424832;                               // 65536
    int*   tidx = (int*)(ws + 2490368);                      // 2048
    unsigned short* lnsc = (unsigned short*)(ws + 2492416);  // 6291456 bf16
    float* lpre = ws + 2492416 + 3145728;                    // 4194304
    unsigned short* wt   = (unsigned short*)(ws + 14026752); // 49152 bf16
    unsigned short* w1t  = (unsigned short*)(ws + 14051328); // 65536 bf16
    unsigned short* w2t  = (unsigned short*)(ws + 14084096); // 65536 bf16
    unsigned short* projt = (unsigned short*)(ws + 14116864); // 16384 bf16
    unsigned short* gw1t  = (unsigned short*)(ws + 14125056); // 65536 bf16
    unsigned short* gw2t  = (unsigned short*)(ws + 14157824); // 65536 bf16
    unsigned short* wot   = (unsigned short*)(ws + 14190592); // 16384 bf16
    unsigned short* qkvt  = (unsigned short*)(ws + 14198784); // 49152 bf16

    const size_t L_OUT = (size_t)BATCH * CDIM * NSP;
    float* gout = out + L_OUT;

    hipLaunchKernelGGL(k_wprep_all, dim3(192), dim3(256), 0, stream,
                       gqkv_w, m2_w1, m2_w2, proj_w, mlp_w1, mlp_w2, wo_w, qkv_w,
                       wt, w1t, w2t, projt, gw1t, gw2t, wot, qkvt);
    hipLaunchKernelGGL(k_gqkv_mfma, dim3(256), dim3(256), 0, stream,
                       xg_in, qkvt, qkv_b, ln_g, ln_b, xg, qgb, kgb, vgtb);
    hipLaunchKernelGGL(k_gattn_mfma, dim3(2048), dim3(256), 0, stream, qgb, kgb, vgtb, og);
    hipLaunchKernelGGL(k_gmlp_mfma, dim3(256), dim3(256), 0, stream,
                       og, xg, projt, proj_b, ln_g, ln_b, gw1t, mlp_b1, gw2t, mlp_b2,
                       xg4, gout);
    hipLaunchKernelGGL(k_routing_qk, dim3(512), dim3(128), 0, stream,
                       xg4, rq_w, rq_b, rk_w, rk_b, qh, kh);
    hipLaunchKernelGGL(k_topk, dim3(512), dim3(256), 0, stream, qh, kh, tidx);
    hipLaunchKernelGGL(k_lnsc_local, dim3(2048), dim3(256), 0, stream,
                       x_in, ln_g, ln_b, lnsc);
    hipLaunchKernelGGL(k_lnsc_gath, dim3(2048), dim3(256), 0, stream,
                       xg4, tidx, ln_g, ln_b, lnsc);
    hipLaunchKernelGGL(k_local_wo_mfma, dim3(512), dim3(512), 0, stream,
                       lnsc, wt, gqkv_b, wot, wo_b, x_in, lpre);
    hipLaunchKernelGGL(k_mlp2_mfma, dim3(1024), dim3(256), 0, stream,
                       lpre, ln_g, ln_b, w1t, m2_b1, w2t, m2_b2, out);
}

// Round 5
// 246.234 us; speedup vs baseline: 1.0165x; 1.0165x over previous
//
#include <hip/hip_runtime.h>
#include <hip/hip_bf16.h>
#include <math.h>

#define BATCH 2
#define CDIM 128
#define SS 16
#define HH_ 32
#define WW_ 32
#define NSP (SS*HH_*WW_)
#define GS 8
#define GH 16
#define GW 16
#define GN (GS*GH*GW)
#define HEADS 8
#define DH 16
#define NW 256
#define W3L 64
#define W3G 8
#define TOPK 4
#define W3 (W3L + TOPK*W3G)
#define LN_EPS 1e-6f
#define ROUTE_SCALE 0.08838834764831845f
#define GATTN_SCALE 0.25f

typedef short bshort8 __attribute__((ext_vector_type(8)));
typedef float f32x4 __attribute__((ext_vector_type(4)));

__device__ __forceinline__ unsigned short f2bf(float f) {
    unsigned int u = __float_as_uint(f);
    unsigned int r = (u + 0x7fffu + ((u >> 16) & 1u)) >> 16;
    return (unsigned short)r;
}
// branchless erf (A&S 7.1.26, |err| < 1.5e-7 — far below bf16 noise)
__device__ __forceinline__ float gelu_exact(float x) {
    float z = x * 0.70710678118654752f;
    float az = fabsf(z);
    float t = 1.0f / fmaf(0.3275911f, az, 1.0f);
    float poly = t * fmaf(t, fmaf(t, fmaf(t, fmaf(t, 1.061405429f, -1.453152027f),
                     1.421413741f), -0.284496736f), 0.254829592f);
    float e = __expf(-az * az);
    float erfv = 1.0f - poly * e;
    erfv = (z < 0.f) ? -erfv : erfv;
    return 0.5f * x * (1.0f + erfv);
}
__device__ __forceinline__ float shfl_sum32(float v) {
#pragma unroll
    for (int m = 16; m > 0; m >>= 1) v += __shfl_xor(v, m);
    return v;
}
__device__ __forceinline__ float shfl_sum16(float v) {
#pragma unroll
    for (int m = 8; m > 0; m >>= 1) v += __shfl_xor(v, m);
    return v;
}
__device__ __forceinline__ float shfl_sum8(float v) {
#pragma unroll
    for (int m = 4; m > 0; m >>= 1) v += __shfl_xor(v, m);
    return v;
}

// ---------------- K0 (FAT): weight prep (blocks 0..191) + local-token LN (blocks 192..2239) ----
// Weight prep -> FRAGMENT-ORDERED bf16:
// wf[((tile*KS + ks)*64 + lane)*8 + e] = W_src[(ks*32 + (lane>>4)*8 + e) * OUT + tile*16 + (lane&15)]
__global__ __launch_bounds__(256) void k_prep_fat(const float* __restrict__ gqkv_w,
        const float* __restrict__ m2_w1, const float* __restrict__ m2_w2,
        const float* __restrict__ proj_w, const float* __restrict__ mlp_w1,
        const float* __restrict__ mlp_w2, const float* __restrict__ wo_w,
        const float* __restrict__ qkv_w,
        unsigned short* __restrict__ wt, unsigned short* __restrict__ w1t,
        unsigned short* __restrict__ w2t, unsigned short* __restrict__ projt,
        unsigned short* __restrict__ gw1t, unsigned short* __restrict__ gw2t,
        unsigned short* __restrict__ wot, unsigned short* __restrict__ qkvt,
        const float* __restrict__ x_in, const float* __restrict__ ln_g,
        const float* __restrict__ ln_b, unsigned short* __restrict__ lnsc) {
    __shared__ float tile[16][132];
    int t = threadIdx.x;
    if (blockIdx.x < 192) {
        // ---- weight prep ----
        int id = blockIdx.x * 256 + t;   // 0..49151
        int frag = id >> 6, lane = id & 63;
        int l15 = lane & 15, quad = lane >> 4;
        const float* srcw; unsigned short* dstw; int KS, OUT, lf; float sc = 1.f;
        if (frag < 96)        { lf = frag;       srcw = gqkv_w; dstw = wt;    KS = 4;  OUT = 384; if ((lf >> 2) < 8) sc = ROUTE_SCALE; }
        else if (frag < 224)  { lf = frag - 96;  srcw = m2_w1;  dstw = w1t;   KS = 4;  OUT = 512; }
        else if (frag < 352)  { lf = frag - 224; srcw = m2_w2;  dstw = w2t;   KS = 16; OUT = 128; }
        else if (frag < 384)  { lf = frag - 352; srcw = proj_w; dstw = projt; KS = 4;  OUT = 128; }
        else if (frag < 512)  { lf = frag - 384; srcw = mlp_w1; dstw = gw1t;  KS = 4;  OUT = 512; }
        else if (frag < 640)  { lf = frag - 512; srcw = mlp_w2; dstw = gw2t;  KS = 16; OUT = 128; }
        else if (frag < 672)  { lf = frag - 640; srcw = wo_w;   dstw = wot;   KS = 4;  OUT = 128; }
        else                  { lf = frag - 672; srcw = qkv_w;  dstw = qkvt;  KS = 4;  OUT = 384; if ((lf >> 2) < 8) sc = GATTN_SCALE; }
        int ksh = (KS == 16) ? 4 : 2;
        int tle = lf >> ksh, ks = lf & (KS - 1);
        int n = tle * 16 + l15;
        int k0 = ks * 32 + quad * 8;
        const float* s = srcw + (size_t)k0 * OUT + n;
        unsigned short o[8];
#pragma unroll
        for (int e = 0; e < 8; e++) o[e] = f2bf(s[(size_t)e * OUT] * sc);
        unsigned short* d = dstw + ((size_t)lf * 64 + lane) * 8;
        *(ushort4*)d = *(ushort4*)&o[0];
        *(ushort4*)(d + 4) = *(ushort4*)&o[4];
        return;
    }
    // ---- local-token LN -> lnsc (windowed layout) ----
    int blk = blockIdx.x - 192;
    int wtile = blk & 1; int hh = (blk >> 1) & 31; int s = (blk >> 6) & 15; int b = blk >> 10;
    int w0 = wtile * 16;
    {
        int c = t >> 1; int wq = (t & 1) * 8;
        const float* src = x_in + (((size_t)(b * 128 + c) * SS + s)) * 1024 + hh * 32 + w0 + wq;
        float4 v0 = *(const float4*)src;
        float4 v1 = *(const float4*)(src + 4);
        tile[wq + 0][c] = v0.x; tile[wq + 1][c] = v0.y; tile[wq + 2][c] = v0.z; tile[wq + 3][c] = v0.w;
        tile[wq + 4][c] = v1.x; tile[wq + 5][c] = v1.y; tile[wq + 6][c] = v1.z; tile[wq + 7][c] = v1.w;
    }
    __syncthreads();
    int w = t >> 4; int j = t & 15;
    float vals[8];
    float s1 = 0.f;
#pragma unroll
    for (int i = 0; i < 8; i++) { vals[i] = tile[w][j * 8 + i]; s1 += vals[i]; }
    s1 = shfl_sum16(s1);
    float mu = s1 * (1.0f / 128.0f);
    float s2 = 0.f;
#pragma unroll
    for (int i = 0; i < 8; i++) { float d = vals[i] - mu; s2 += d * d; }
    s2 = shfl_sum16(s2);
    float rs = rsqrtf(s2 * (1.0f / 128.0f) + LN_EPS);
    float4 g0 = *(const float4*)(ln_g + j * 8);
    float4 g1 = *(const float4*)(ln_g + j * 8 + 4);
    float4 b0 = *(const float4*)(ln_b + j * 8);
    float4 b1 = *(const float4*)(ln_b + j * 8 + 4);
    float gv[8] = { g0.x, g0.y, g0.z, g0.w, g1.x, g1.y, g1.z, g1.w };
    float bv[8] = { b0.x, b0.y, b0.z, b0.w, b1.x, b1.y, b1.z, b1.w };
    int ww = w0 + w;
    int n = (s >> 2) * 64 + (hh >> 2) * 8 + (ww >> 2);
    int slot = (s & 3) * 16 + (hh & 3) * 4 + (ww & 3);
    unsigned short* dst = lnsc + ((size_t)(b * NW + n) * W3 + slot) * 128 + j * 8;
    ushort4 u0, u1;
    u0.x = f2bf((vals[0] - mu) * rs * gv[0] + bv[0]);
    u0.y = f2bf((vals[1] - mu) * rs * gv[1] + bv[1]);
    u0.z = f2bf((vals[2] - mu) * rs * gv[2] + bv[2]);
    u0.w = f2bf((vals[3] - mu) * rs * gv[3] + bv[3]);
    u1.x = f2bf((vals[4] - mu) * rs * gv[4] + bv[4]);
    u1.y = f2bf((vals[5] - mu) * rs * gv[5] + bv[5]);
    u1.z = f2bf((vals[6] - mu) * rs * gv[6] + bv[6]);
    u1.w = f2bf((vals[7] - mu) * rs * gv[7] + bv[7]);
    *(ushort4*)dst = u0;
    *(ushort4*)(dst + 4) = u1;
}

// ---------------- K1: global branch qkv via MFMA, 16 tokens/block (256 blocks) ----------------
__global__ __launch_bounds__(256) void k_gqkv_mfma(const float* __restrict__ xg_in,
        const unsigned short* __restrict__ qkvt, const float* __restrict__ qkv_b,
        const float* __restrict__ ln_g, const float* __restrict__ ln_b,
        float* __restrict__ xg, unsigned short* __restrict__ qgb,
        unsigned short* __restrict__ kgb, unsigned short* __restrict__ vgtb) {
    int blk = blockIdx.x; int b = blk >> 7; int n0 = (blk & 127) * 16;
    int t = threadIdx.x; int w = t >> 6; int lane = t & 63;
    int l15 = lane & 15, quad = lane >> 4;
    __shared__ __align__(16) float xs[16 * 132];
    __shared__ __align__(16) unsigned short h[16 * 136];
    f32x4 zero4 = {0.f, 0.f, 0.f, 0.f};

    {   // transpose load: thread t -> channel c, token-octet
        int c = t >> 1, j0 = (t & 1) * 8;
        const float* src = xg_in + ((size_t)(b * 128 + c)) * GN + n0 + j0;
        float4 v0 = *(const float4*)src;
        float4 v1 = *(const float4*)(src + 4);
        xs[(j0 + 0) * 132 + c] = v0.x; xs[(j0 + 1) * 132 + c] = v0.y;
        xs[(j0 + 2) * 132 + c] = v0.z; xs[(j0 + 3) * 132 + c] = v0.w;
        xs[(j0 + 4) * 132 + c] = v1.x; xs[(j0 + 5) * 132 + c] = v1.y;
        xs[(j0 + 6) * 132 + c] = v1.z; xs[(j0 + 7) * 132 + c] = v1.w;
    }
    __syncthreads();
    {   // LN: 16 threads/token, 8 ch each; write xg fp32 + h bf16
        int j = t >> 4, p = t & 15, c0 = p * 8;
        float vv[8]; float s1 = 0.f;
#pragma unroll
        for (int i = 0; i < 8; i++) { vv[i] = xs[j * 132 + c0 + i]; s1 += vv[i]; }
        s1 = shfl_sum16(s1);
        float mu = s1 * (1.0f / 128.0f);
        float s2 = 0.f;
#pragma unroll
        for (int i = 0; i < 8; i++) { float d = vv[i] - mu; s2 += d * d; }
        s2 = shfl_sum16(s2);
        float rs = rsqrtf(s2 * (1.0f / 128.0f) + LN_EPS);
        float* dst = xg + ((size_t)(b * GN) + n0 + j) * 128 + c0;
        *(float4*)dst = *(float4*)&vv[0];
        *(float4*)(dst + 4) = *(float4*)&vv[4];
        unsigned short hb[8];
#pragma unroll
        for (int i4 = 0; i4 < 2; i4++) {
            float4 g4 = *(const float4*)(ln_g + c0 + i4 * 4);
            float4 b4 = *(const float4*)(ln_b + c0 + i4 * 4);
            hb[i4 * 4 + 0] = f2bf((vv[i4 * 4 + 0] - mu) * rs * g4.x + b4.x);
            hb[i4 * 4 + 1] = f2bf((vv[i4 * 4 + 1] - mu) * rs * g4.y + b4.y);
            hb[i4 * 4 + 2] = f2bf((vv[i4 * 4 + 2] - mu) * rs * g4.z + b4.z);
            hb[i4 * 4 + 3] = f2bf((vv[i4 * 4 + 3] - mu) * rs * g4.w + b4.w);
        }
        *(ushort4*)&h[j * 136 + c0] = *(ushort4*)&hb[0];
        *(ushort4*)&h[j * 136 + c0 + 4] = *(ushort4*)&hb[4];
    }
    __syncthreads();

    bshort8 a[4];
#pragma unroll
    for (int ks = 0; ks < 4; ks++)
        a[ks] = *(const bshort8*)(h + l15 * 136 + ks * 32 + quad * 8);
    int bh_base = b * HEADS;
#pragma unroll
    for (int part = 0; part < 2; part++) {
#pragma unroll
        for (int which = 0; which < 2; which++) {
            int nt = 2 * w + which;
            f32x4 acc = zero4;
#pragma unroll
            for (int ks = 0; ks < 4; ks++) {
                bshort8 bfr = *(const bshort8*)(qkvt + (((size_t)(part * 8 + nt) * 4 + ks) * 64 + lane) * 8);
                acc = __builtin_amdgcn_mfma_f32_16x16x32_bf16(a[ks], bfr, acc, 0, 0, 0);
            }
            int ncol = part * 128 + nt * 16;
            float bias = qkv_b[ncol + l15] * (part == 0 ? GATTN_SCALE : 1.f);
            unsigned short* dst = (part == 0) ? qgb : kgb;
#pragma unroll
            for (int r = 0; r < 4; r++)
                dst[((size_t)(bh_base + nt) * GN + n0 + quad * 4 + r) * DH + l15] = f2bf(acc[r] + bias);
        }
    }
#pragma unroll
    for (int which = 0; which < 2; which++) {
        int mtv = 2 * w + which;
        f32x4 acc = zero4;
#pragma unroll
        for (int ks = 0; ks < 4; ks++) {
            bshort8 aw = *(const bshort8*)(qkvt + (((size_t)(16 + mtv) * 4 + ks) * 64 + lane) * 8);
            acc = __builtin_amdgcn_mfma_f32_16x16x32_bf16(aw, a[ks], acc, 0, 0, 0);
        }
#pragma unroll
        for (int r = 0; r < 4; r++) {
            float bias = qkv_b[256 + mtv * 16 + quad * 4 + r];
            vgtb[((size_t)(bh_base + mtv) * DH + quad * 4 + r) * GN + n0 + l15] = f2bf(acc[r] + bias);
        }
    }
}

// ---------------- K2: global attention via MFMA bf16 ----------------
__global__ __launch_bounds__(256) void k_gattn_mfma(const unsigned short* __restrict__ qgb,
        const unsigned short* __restrict__ kgb, const unsigned short* __restrict__ vgtb,
        float* __restrict__ og) {
    int blk = blockIdx.x;
    int bh = blk >> 7; int qt = (blk & 127) << 4;
    int b = bh >> 3, hh = bh & 7;
    int t = threadIdx.x; int w = t >> 6; int lane = t & 63;
    int col = lane & 15, quad = lane >> 4;
    __shared__ __align__(16) unsigned short Pbuf[4 * 16 * 40];
    __shared__ float po[4][64][4];
    __shared__ float pl[4][64][4];

    bshort8 aq = {0, 0, 0, 0, 0, 0, 0, 0};
    if (quad < 2)
        aq = *(const bshort8*)(qgb + ((size_t)bh * GN + qt + col) * DH + quad * 8);

    f32x4 o = {0.f, 0.f, 0.f, 0.f};
    float lsum[4] = {0.f, 0.f, 0.f, 0.f};
    const unsigned short* kb = kgb + (size_t)bh * GN * DH;
    const unsigned short* vb = vgtb + (size_t)bh * DH * GN;
    unsigned short* pb = Pbuf + w * (16 * 40);
    int row0 = quad * 4;
    int kbeg = w * 512;
    for (int kc = kbeg; kc < kbeg + 512; kc += 32) {
        bshort8 bk0 = {0, 0, 0, 0, 0, 0, 0, 0};
        bshort8 bk1 = {0, 0, 0, 0, 0, 0, 0, 0};
        if (quad < 2) {
            bk0 = *(const bshort8*)(kb + (size_t)(kc + col) * DH + quad * 8);
            bk1 = *(const bshort8*)(kb + (size_t)(kc + 16 + col) * DH + quad * 8);
        }
        f32x4 z = {0.f, 0.f, 0.f, 0.f};
        f32x4 s0 = __builtin_amdgcn_mfma_f32_16x16x32_bf16(aq, bk0, z, 0, 0, 0);
        f32x4 s1 = __builtin_amdgcn_mfma_f32_16x16x32_bf16(aq, bk1, z, 0, 0, 0);
        float p0[4], p1[4];
#pragma unroll
        for (int r = 0; r < 4; r++) {
            p0[r] = __expf(s0[r]); p1[r] = __expf(s1[r]);
            lsum[r] += p0[r] + p1[r];
        }
#pragma unroll
        for (int r = 0; r < 4; r++) {
            pb[(row0 + r) * 40 + col] = f2bf(p0[r]);
            pb[(row0 + r) * 40 + 16 + col] = f2bf(p1[r]);
        }
        bshort8 pA = *(const bshort8*)(pb + col * 40 + quad * 8);
        bshort8 bv = *(const bshort8*)(vb + (size_t)col * GN + kc + quad * 8);
        o = __builtin_amdgcn_mfma_f32_16x16x32_bf16(pA, bv, o, 0, 0, 0);
    }
#pragma unroll
    for (int r = 0; r < 4; r++) {
        float v = lsum[r];
        v += __shfl_xor(v, 1); v += __shfl_xor(v, 2);
        v += __shfl_xor(v, 4); v += __shfl_xor(v, 8);
        lsum[r] = v;
    }
#pragma unroll
    for (int r = 0; r < 4; r++) { po[w][lane][r] = o[r]; pl[w][lane][r] = lsum[r]; }
    __syncthreads();
    {   // combine distributed across all 4 waves: wave w handles r = w
        float os = po[0][lane][w] + po[1][lane][w] + po[2][lane][w] + po[3][lane][w];
        float ls = pl[0][lane][w] + pl[1][lane][w] + pl[2][lane][w] + pl[3][lane][w];
        og[((size_t)(b * GN) + qt + quad * 4 + w) * 128 + hh * 16 + col] = os / ls;
    }
}

// ---------------- K3: global proj+residual+LN+MLP via MFMA, 16 tokens/block ----------------
__global__ __launch_bounds__(256) void k_gmlp_mfma(const float* __restrict__ og,
        const float* __restrict__ xg,
        const unsigned short* __restrict__ projt, const float* __restrict__ proj_b,
        const float* __restrict__ ln_g, const float* __restrict__ ln_b,
        const unsigned short* __restrict__ gw1t, const float* __restrict__ b1,
        const unsigned short* __restrict__ gw2t, const float* __restrict__ b2,
        float* __restrict__ xg4, float* __restrict__ gout) {
    int blk = blockIdx.x; int b = blk >> 7; int n0g = (blk & 127) * 16;
    int t = threadIdx.x; int w = t >> 6; int lane = t & 63;
    int l15 = lane & 15, quad = lane >> 4;
    __shared__ __align__(16) unsigned short ao[16 * 136];
    __shared__ __align__(16) float xs[16 * 132];
    __shared__ __align__(16) unsigned short h[16 * 136];
    __shared__ __align__(16) unsigned short h1[16 * 520];
    float* of32 = (float*)h1;
    f32x4 zero4 = {0.f, 0.f, 0.f, 0.f};

    {
        int j = t >> 4, p = t & 15, c0 = p * 8;
        size_t base = ((size_t)(b * GN) + n0g + j) * 128 + c0;
        float4 v0 = *(const float4*)(og + base);
        float4 v1 = *(const float4*)(og + base + 4);
        ushort4 u0 = { f2bf(v0.x), f2bf(v0.y), f2bf(v0.z), f2bf(v0.w) };
        ushort4 u1 = { f2bf(v1.x), f2bf(v1.y), f2bf(v1.z), f2bf(v1.w) };
        *(ushort4*)&ao[j * 136 + c0] = u0;
        *(ushort4*)&ao[j * 136 + c0 + 4] = u1;
        *(float4*)&xs[j * 132 + c0] = *(const float4*)(xg + base);
        *(float4*)&xs[j * 132 + c0 + 4] = *(const float4*)(xg + base + 4);
    }
    __syncthreads();

    {
        bshort8 a[4];
#pragma unroll
        for (int ks = 0; ks < 4; ks++)
            a[ks] = *(const bshort8*)(ao + l15 * 136 + ks * 32 + quad * 8);
#pragma unroll
        for (int nt = 0; nt < 2; nt++) {
            f32x4 acc = zero4;
#pragma unroll
            for (int ks = 0; ks < 4; ks++) {
                bshort8 bfr = *(const bshort8*)(projt + (((size_t)(w * 2 + nt) * 4 + ks) * 64 + lane) * 8);
                acc = __builtin_amdgcn_mfma_f32_16x16x32_bf16(a[ks], bfr, acc, 0, 0, 0);
            }
            int n0 = w * 32 + nt * 16;
            float bias = proj_b[n0 + l15];
#pragma unroll
            for (int r = 0; r < 4; r++) {
                int m = quad * 4 + r;
                xs[m * 132 + n0 + l15] += acc[r] + bias;
            }
        }
    }
    __syncthreads();

    {
        int j = t >> 4, p = t & 15, c0 = p * 8;
        float vv[8]; float s1 = 0.f;
#pragma unroll
        for (int i = 0; i < 8; i++) { vv[i] = xs[j * 132 + c0 + i]; s1 += vv[i]; }
        s1 = shfl_sum16(s1);
        float mu = s1 * (1.0f / 128.0f);
        float s2 = 0.f;
#pragma unroll
        for (int i = 0; i < 8; i++) { float d = vv[i] - mu; s2 += d * d; }
        s2 = shfl_sum16(s2);
        float rs = rsqrtf(s2 * (1.0f / 128.0f) + LN_EPS);
        unsigned short hb[8];
#pragma unroll
        for (int i4 = 0; i4 < 2; i4++) {
            float4 g4 = *(const float4*)(ln_g + c0 + i4 * 4);
            float4 b4 = *(const float4*)(ln_b + c0 + i4 * 4);
            hb[i4 * 4 + 0] = f2bf((vv[i4 * 4 + 0] - mu) * rs * g4.x + b4.x);
            hb[i4 * 4 + 1] = f2bf((vv[i4 * 4 + 1] - mu) * rs * g4.y + b4.y);
            hb[i4 * 4 + 2] = f2bf((vv[i4 * 4 + 2] - mu) * rs * g4.z + b4.z);
            hb[i4 * 4 + 3] = f2bf((vv[i4 * 4 + 3] - mu) * rs * g4.w + b4.w);
        }
        *(ushort4*)&h[j * 136 + c0] = *(ushort4*)&hb[0];
        *(ushort4*)&h[j * 136 + c0 + 4] = *(ushort4*)&hb[4];
    }
    __syncthreads();

    {
        bshort8 a[4];
#pragma unroll
        for (int ks = 0; ks < 4; ks++)
            a[ks] = *(const bshort8*)(h + l15 * 136 + ks * 32 + quad * 8);
#pragma unroll
        for (int nt = 0; nt < 8; nt++) {
            f32x4 acc = zero4;
#pragma unroll
            for (int ks = 0; ks < 4; ks++) {
                bshort8 bfr = *(const bshort8*)(gw1t + (((size_t)(w * 8 + nt) * 4 + ks) * 64 + lane) * 8);
                acc = __builtin_amdgcn_mfma_f32_16x16x32_bf16(a[ks], bfr, acc, 0, 0, 0);
            }
            int n0 = w * 128 + nt * 16;
            float bias = b1[n0 + l15];
#pragma unroll
            for (int r = 0; r < 4; r++)
                h1[(quad * 4 + r) * 520 + n0 + l15] = f2bf(gelu_exact(acc[r] + bias));
        }
    }
    __syncthreads();

    f32x4 acc2[2]; acc2[0] = zero4; acc2[1] = zero4;
#pragma unroll 4
    for (int ks = 0; ks < 16; ks++) {
        bshort8 a = *(const bshort8*)(h1 + l15 * 520 + ks * 32 + quad * 8);
#pragma unroll
        for (int nt = 0; nt < 2; nt++) {
            bshort8 bfr = *(const bshort8*)(gw2t + (((size_t)(w * 2 + nt) * 16 + ks) * 64 + lane) * 8);
            acc2[nt] = __builtin_amdgcn_mfma_f32_16x16x32_bf16(a, bfr, acc2[nt], 0, 0, 0);
        }
    }
    __syncthreads();

    {
#pragma unroll
        for (int nt = 0; nt < 2; nt++) {
            int n0 = w * 32 + nt * 16;
            float bias = b2[n0 + l15];
#pragma unroll
            for (int r = 0; r < 4; r++) {
                int m = quad * 4 + r;
                float ov = xs[m * 132 + n0 + l15] + acc2[nt][r] + bias;
                of32[m * 132 + n0 + l15] = ov;
                xg4[((size_t)(b * GN) + n0g + m) * 128 + n0 + l15] = ov;
            }
        }
    }
    __syncthreads();

    {
        int cw = t >> 1, hf = t & 1, j0 = hf * 8;
        float* dst = gout + ((size_t)(b * 128 + cw)) * GN + n0g + j0;
#pragma unroll
        for (int i4 = 0; i4 < 2; i4++) {
            float4 ov = { of32[(j0 + i4 * 4 + 0) * 132 + cw], of32[(j0 + i4 * 4 + 1) * 132 + cw],
                          of32[(j0 + i4 * 4 + 2) * 132 + cw], of32[(j0 + i4 * 4 + 3) * 132 + cw] };
            *(float4*)(dst + i4 * 4) = ov;
        }
    }
}

// ---------------- K4a: routing q/k ----------------
__global__ void k_routing_qk(const float* __restrict__ xg4,
                             const float* __restrict__ rq_w, const float* __restrict__ rq_b,
                             const float* __restrict__ rk_w, const float* __restrict__ rk_b,
                             float* __restrict__ qh, float* __restrict__ kh) {
    int wid = blockIdx.x; int b = wid / NW, n = wid % NW;
    int c = threadIdx.x;
    int i1 = n / 64, i2 = (n / 8) % 8, i3 = n % 8;
    __shared__ float g[CDIM];
    float s = 0.f;
#pragma unroll
    for (int j = 0; j < W3G; j++) {
        int ds = j >> 2, dh = (j >> 1) & 1, dw = j & 1;
        int gi = ((i1 * 2 + ds) * GH + (i2 * 2 + dh)) * GW + (i3 * 2 + dw);
        s += xg4[((size_t)(b * GN + gi)) * CDIM + c];
    }
    g[c] = s * (1.0f / W3G);
    __syncthreads();
    float aq = rq_b[c], ak = rk_b[c];
    for (int k = 0; k < CDIM; k++) { float gv = g[k]; aq = fmaf(gv, rq_w[k * CDIM + c], aq); ak = fmaf(gv, rk_w[k * CDIM + c], ak); }
    qh[(size_t)wid * CDIM + c] = aq;
    kh[(size_t)wid * CDIM + c] = ak;
}

// ---------------- K4b: top-k + gather/LN of selected global windows (absorbs k_lnsc_gath) ----
__global__ __launch_bounds__(256) void k_topk_gath(const float* __restrict__ qh,
        const float* __restrict__ kh, const float* __restrict__ xg4,
        const float* __restrict__ ln_g, const float* __restrict__ ln_b,
        unsigned short* __restrict__ lnsc) {
    int wid = blockIdx.x; int b = wid / NW;
    int m = threadIdx.x;
    __shared__ float q[CDIM];
    __shared__ float lv[NW];
    __shared__ int li[NW];
    __shared__ int sel4[TOPK];
    if (m < CDIM) q[m] = qh[(size_t)wid * CDIM + m] * ROUTE_SCALE;
    __syncthreads();
    float acc = 0.f;
    const float* kr = kh + ((size_t)b * NW + m) * CDIM;
    for (int k = 0; k < CDIM; k++) acc = fmaf(q[k], kr[k], acc);
#pragma unroll
    for (int sel = 0; sel < TOPK; sel++) {
        lv[m] = acc; li[m] = m; __syncthreads();
#pragma unroll
        for (int s = 128; s > 0; s >>= 1) {
            if (m < s) {
                if (lv[m + s] > lv[m] || (lv[m + s] == lv[m] && li[m + s] < li[m])) {
                    lv[m] = lv[m + s]; li[m] = li[m + s];
                }
            }
            __syncthreads();
        }
        int best = li[0]; __syncthreads();
        if (m == best) acc = -1e30f;
        if (m == 0) sel4[sel] = best;
    }
    __syncthreads();

    // gather + LN: 32 tokens (4 windows x 8), 8 threads/token x 16 ch
    {
        int tt = m >> 3, p = m & 7, ch0 = p * 16;
        int kk = tt >> 3, j = tt & 7;
        int g = sel4[kk];
        int gi1 = g >> 6, gi2 = (g >> 3) & 7, gi3 = g & 7;
        int ds = j >> 2, dh = (j >> 1) & 1, dw = j & 1;
        int gi = ((gi1 * 2 + ds) * GH + (gi2 * 2 + dh)) * GW + (gi3 * 2 + dw);
        const float* src = xg4 + ((size_t)(b * GN + gi)) * CDIM + ch0;
        float4 v0 = *(const float4*)(src);
        float4 v1 = *(const float4*)(src + 4);
        float4 v2 = *(const float4*)(src + 8);
        float4 v3 = *(const float4*)(src + 12);
        float vv[16] = { v0.x, v0.y, v0.z, v0.w, v1.x, v1.y, v1.z, v1.w,
                         v2.x, v2.y, v2.z, v2.w, v3.x, v3.y, v3.z, v3.w };
        float s1 = 0.f;
#pragma unroll
        for (int i = 0; i < 16; i++) s1 += vv[i];
        s1 = shfl_sum8(s1);
        float mu = s1 * (1.0f / 128.0f);
        float s2 = 0.f;
#pragma unroll
        for (int i = 0; i < 16; i++) { float d = vv[i] - mu; s2 += d * d; }
        s2 = shfl_sum8(s2);
        float rs = rsqrtf(s2 * (1.0f / 128.0f) + LN_EPS);
        unsigned short hb[16];
#pragma unroll
        for (int i4 = 0; i4 < 4; i4++) {
            float4 g4 = *(const float4*)(ln_g + ch0 + i4 * 4);
            float4 b4 = *(const float4*)(ln_b + ch0 + i4 * 4);
            hb[i4 * 4 + 0] = f2bf((vv[i4 * 4 + 0] - mu) * rs * g4.x + b4.x);
            hb[i4 * 4 + 1] = f2bf((vv[i4 * 4 + 1] - mu) * rs * g4.y + b4.y);
            hb[i4 * 4 + 2] = f2bf((vv[i4 * 4 + 2] - mu) * rs * g4.z + b4.z);
            hb[i4 * 4 + 3] = f2bf((vv[i4 * 4 + 3] - mu) * rs * g4.w + b4.w);
        }
        unsigned short* dst = lnsc + ((size_t)wid * W3 + 64 + kk * 8 + j) * 128 + ch0;
        *(ushort4*)(dst + 0) = *(ushort4*)&hb[0];
        *(ushort4*)(dst + 4) = *(ushort4*)&hb[4];
        *(ushort4*)(dst + 8) = *(ushort4*)&hb[8];
        *(ushort4*)(dst + 12) = *(ushort4*)&hb[12];
    }
}

// ---------------- K6: FUSED local attention + wo projection + shortcut ----------------
__global__ __launch_bounds__(512, 4) void k_local_wo_mfma(const unsigned short* __restrict__ lnsc,
        const unsigned short* __restrict__ wt, const float* __restrict__ gqkv_b,
        const unsigned short* __restrict__ wot, const float* __restrict__ wo_b,
        const float* __restrict__ x_in, float* __restrict__ lpre) {
    int wn = blockIdx.x;
    int b = wn >> 8; int n = wn & 255;
    int i1 = n >> 6, i2 = (n >> 3) & 7, i3 = n & 7;
    int s0 = i1 * 4, h0 = i2 * 4, w0 = i3 * 4;
    int t = threadIdx.x; int w = t >> 6; int lane = t & 63;
    int l15 = lane & 15, quad = lane >> 4;
    __shared__ __align__(16) unsigned short SMEM[64 * 136 + 96 * 136 + 128 * 104 + 8 * 640];
    unsigned short* Qs  = SMEM;
    unsigned short* Ks2 = SMEM + 64 * 136;
    unsigned short* Vts = SMEM + 64 * 136 + 96 * 136;
    unsigned short* Ps  = SMEM + 64 * 136 + 96 * 136 + 128 * 104;
    float* xs = (float*)Ks2;

    const unsigned short* Xb = lnsc + (size_t)wn * W3 * 128;
    f32x4 zero4 = {0.f, 0.f, 0.f, 0.f};

    int cx = t >> 2, sub = t & 3;
    float4 xr[4];
#pragma unroll
    for (int i = 0; i < 4; i++) {
        int jr = sub * 4 + i;
        int ds = jr >> 2, dh = jr & 3;
        xr[i] = *(const float4*)(x_in + ((size_t)(b * 128 + cx)) * 16384
                                 + (size_t)(s0 + ds) * 1024 + (h0 + dh) * 32 + w0);
    }

    bshort8 qw[4], kw[4], vw[4];
#pragma unroll
    for (int ks = 0; ks < 4; ks++) {
        qw[ks] = *(const bshort8*)(wt + (((size_t)(0 + w) * 4 + ks) * 64 + lane) * 8);
        kw[ks] = *(const bshort8*)(wt + (((size_t)(8 + w) * 4 + ks) * 64 + lane) * 8);
        vw[ks] = *(const bshort8*)(wt + (((size_t)(16 + w) * 4 + ks) * 64 + lane) * 8);
    }
    float qbias = gqkv_b[w * 16 + l15] * ROUTE_SCALE;
    float kbias = gqkv_b[128 + w * 16 + l15];
    float vbias[4];
#pragma unroll
    for (int r = 0; r < 4; r++) vbias[r] = gqkv_b[256 + w * 16 + quad * 4 + r];

    for (int mt = 0; mt < 6; mt++) {
        bshort8 a[4];
#pragma unroll
        for (int ks = 0; ks < 4; ks++)
            a[ks] = *(const bshort8*)(Xb + (mt * 16 + l15) * 128 + ks * 32 + quad * 8);
        f32x4 acck = zero4;
        f32x4 accv = zero4;
#pragma unroll
        for (int ks = 0; ks < 4; ks++) {
            acck = __builtin_amdgcn_mfma_f32_16x16x32_bf16(a[ks], kw[ks], acck, 0, 0, 0);
            accv = __builtin_amdgcn_mfma_f32_16x16x32_bf16(vw[ks], a[ks], accv, 0, 0, 0);
        }
#pragma unroll
        for (int r = 0; r < 4; r++) {
            Ks2[(mt * 16 + quad * 4 + r) * 136 + w * 16 + l15] = f2bf(acck[r] + kbias);
            Vts[(w * 16 + quad * 4 + r) * 104 + mt * 16 + l15] = f2bf(accv[r] + vbias[r]);
        }
        if (mt < 4) {
            f32x4 accq = zero4;
#pragma unroll
            for (int ks = 0; ks < 4; ks++)
                accq = __builtin_amdgcn_mfma_f32_16x16x32_bf16(a[ks], qw[ks], accq, 0, 0, 0);
#pragma unroll
            for (int r = 0; r < 4; r++)
                Qs[(mt * 16 + quad * 4 + r) * 136 + w * 16 + l15] = f2bf(accq[r] + qbias);
        }
    }
    // no barrier: wave w's attention reads only its own LDS column slices.

    unsigned short* Pw = Ps + w * 640;
    bshort8 zfrag = {0, 0, 0, 0, 0, 0, 0, 0};
    int h = w;
    for (int mt = 0; mt < 4; mt++) {
        bshort8 aq = zfrag;
        if (quad < 2)
            aq = *(const bshort8*)(Qs + (mt * 16 + l15) * 136 + h * 16 + quad * 8);
        float rsum[4] = {0.f, 0.f, 0.f, 0.f};
        f32x4 oacc = zero4;
#pragma unroll
        for (int kc = 0; kc < 96; kc += 32) {
#pragma unroll
            for (int sub2 = 0; sub2 < 2; sub2++) {
                int nt = (kc >> 4) + sub2;
                bshort8 bk = zfrag;
                if (quad < 2)
                    bk = *(const bshort8*)(Ks2 + (nt * 16 + l15) * 136 + h * 16 + quad * 8);
                f32x4 s = __builtin_amdgcn_mfma_f32_16x16x32_bf16(aq, bk, zero4, 0, 0, 0);
#pragma unroll
                for (int r = 0; r < 4; r++) {
                    float p = __expf(s[r]);
                    rsum[r] += p;
                    Pw[(quad * 4 + r) * 40 + sub2 * 16 + l15] = f2bf(p);
                }
            }
            bshort8 ap = *(const bshort8*)(Pw + l15 * 40 + quad * 8);
            bshort8 bv = *(const bshort8*)(Vts + (h * 16 + l15) * 104 + kc + quad * 8);
            oacc = __builtin_amdgcn_mfma_f32_16x16x32_bf16(ap, bv, oacc, 0, 0, 0);
        }
#pragma unroll
        for (int r = 0; r < 4; r++) {
            float v = rsum[r];
            v += __shfl_xor(v, 1); v += __shfl_xor(v, 2);
            v += __shfl_xor(v, 4); v += __shfl_xor(v, 8);
            rsum[r] = v;
        }
#pragma unroll
        for (int r = 0; r < 4; r++)
            Qs[(mt * 16 + quad * 4 + r) * 136 + h * 16 + l15] = f2bf(oacc[r] / rsum[r]);
    }

    __syncthreads();

#pragma unroll
    for (int i = 0; i < 4; i++) {
        int jr = sub * 4 + i;
        xs[(jr * 4 + 0) * 132 + cx] = xr[i].x;
        xs[(jr * 4 + 1) * 132 + cx] = xr[i].y;
        xs[(jr * 4 + 2) * 132 + cx] = xr[i].z;
        xs[(jr * 4 + 3) * 132 + cx] = xr[i].w;
    }

    float wbias = wo_b[w * 16 + l15];
    bshort8 wow[4];
#pragma unroll
    for (int ks = 0; ks < 4; ks++)
        wow[ks] = *(const bshort8*)(wot + (((size_t)w * 4 + ks) * 64 + lane) * 8);
#pragma unroll
    for (int mt = 0; mt < 4; mt++) {
        bshort8 a[4];
#pragma unroll
        for (int ks = 0; ks < 4; ks++)
            a[ks] = *(const bshort8*)(Qs + (mt * 16 + l15) * 136 + ks * 32 + quad * 8);
        f32x4 acc = zero4;
#pragma unroll
        for (int ks = 0; ks < 4; ks++)
            acc = __builtin_amdgcn_mfma_f32_16x16x32_bf16(a[ks], wow[ks], acc, 0, 0, 0);
#pragma unroll
        for (int r = 0; r < 4; r++) {
            int slot = mt * 16 + quad * 4 + r;
            int ds = slot >> 4, dh = (slot >> 2) & 3, dw = slot & 3;
            int sp = (s0 + ds) * 1024 + (h0 + dh) * 32 + (w0 + dw);
            lpre[((size_t)(b * 16384) + sp) * 128 + w * 16 + l15]
                = acc[r] + wbias + xs[slot * 132 + w * 16 + l15];
        }
    }
}

// ---------------- K8: LN + MLP2 via MFMA, 32 tokens/block ----------------
__global__ __launch_bounds__(256) void k_mlp2_mfma(const float* __restrict__ lpre,
        const float* __restrict__ ln_g, const float* __restrict__ ln_b,
        const unsigned short* __restrict__ w1t, const float* __restrict__ b1,
        const unsigned short* __restrict__ w2t, const float* __restrict__ b2,
        float* __restrict__ lout) {
    int blk = blockIdx.x;
    int T0 = blk * 32;
    int b = T0 >> 14;
    int sp = T0 & 16383;
    int t = threadIdx.x; int w = t >> 6; int lane = t & 63;
    int l15 = lane & 15, quad = lane >> 4;
    __shared__ __align__(16) unsigned short buf[32 * 520];
    float* of32 = (float*)buf;

    float res[2][2][4];
#pragma unroll
    for (int mt = 0; mt < 2; mt++)
#pragma unroll
        for (int nt = 0; nt < 2; nt++)
#pragma unroll
            for (int r = 0; r < 4; r++)
                res[mt][nt][r] = lpre[((size_t)T0 + mt * 16 + quad * 4 + r) * 128 + w * 32 + nt * 16 + l15];

    {
        int j = t >> 3, p = t & 7, c0 = p * 16;
        const float* src = lpre + ((size_t)T0 + j) * 128 + c0;
        float4 v0 = *(const float4*)(src + 0);
        float4 v1 = *(const float4*)(src + 4);
        float4 v2 = *(const float4*)(src + 8);
        float4 v3 = *(const float4*)(src + 12);
        float s1 = (v0.x + v0.y + v0.z + v0.w) + (v1.x + v1.y + v1.z + v1.w)
                 + (v2.x + v2.y + v2.z + v2.w) + (v3.x + v3.y + v3.z + v3.w);
        s1 = shfl_sum8(s1);
        float mu = s1 * (1.0f / 128.0f);
        float vv[16] = { v0.x, v0.y, v0.z, v0.w, v1.x, v1.y, v1.z, v1.w,
                         v2.x, v2.y, v2.z, v2.w, v3.x, v3.y, v3.z, v3.w };
        float s2 = 0.f;
#pragma unroll
        for (int i = 0; i < 16; i++) { float d = vv[i] - mu; s2 += d * d; }
        s2 = shfl_sum8(s2);
        float rs = rsqrtf(s2 * (1.0f / 128.0f) + LN_EPS);
        unsigned short hb[16];
#pragma unroll
        for (int i4 = 0; i4 < 4; i4++) {
            float4 g4 = *(const float4*)(ln_g + c0 + i4 * 4);
            float4 b4 = *(const float4*)(ln_b + c0 + i4 * 4);
            hb[i4 * 4 + 0] = f2bf((vv[i4 * 4 + 0] - mu) * rs * g4.x + b4.x);
            hb[i4 * 4 + 1] = f2bf((vv[i4 * 4 + 1] - mu) * rs * g4.y + b4.y);
            hb[i4 * 4 + 2] = f2bf((vv[i4 * 4 + 2] - mu) * rs * g4.z + b4.z);
            hb[i4 * 4 + 3] = f2bf((vv[i4 * 4 + 3] - mu) * rs * g4.w + b4.w);
        }
        *(ushort4*)&buf[j * 136 + c0 + 0] = *(ushort4*)&hb[0];
        *(ushort4*)&buf[j * 136 + c0 + 4] = *(ushort4*)&hb[4];
        *(ushort4*)&buf[j * 136 + c0 + 8] = *(ushort4*)&hb[8];
        *(ushort4*)&buf[j * 136 + c0 + 12] = *(ushort4*)&hb[12];
    }
    __syncthreads();

    bshort8 a1[2][4];
#pragma unroll
    for (int mt = 0; mt < 2; mt++)
#pragma unroll
        for (int ks = 0; ks < 4; ks++)
            a1[mt][ks] = *(const bshort8*)(buf + (mt * 16 + l15) * 136 + ks * 32 + quad * 8);
    __syncthreads();

    f32x4 zero4 = {0.f, 0.f, 0.f, 0.f};
    {
#pragma unroll
        for (int nt = 0; nt < 8; nt++) {
            int n0 = w * 128 + nt * 16;
            f32x4 acc0 = zero4, acc1 = zero4;
#pragma unroll
            for (int ks = 0; ks < 4; ks++) {
                bshort8 bfr = *(const bshort8*)(w1t + (((size_t)(w * 8 + nt) * 4 + ks) * 64 + lane) * 8);
                acc0 = __builtin_amdgcn_mfma_f32_16x16x32_bf16(a1[0][ks], bfr, acc0, 0, 0, 0);
                acc1 = __builtin_amdgcn_mfma_f32_16x16x32_bf16(a1[1][ks], bfr, acc1, 0, 0, 0);
            }
            float bias = b1[n0 + l15];
#pragma unroll
            for (int r = 0; r < 4; r++) {
                buf[(quad * 4 + r) * 520 + n0 + l15] = f2bf(gelu_exact(acc0[r] + bias));
                buf[(16 + quad * 4 + r) * 520 + n0 + l15] = f2bf(gelu_exact(acc1[r] + bias));
            }
        }
    }
    __syncthreads();

    f32x4 acc[2][2];
    acc[0][0] = zero4; acc[0][1] = zero4; acc[1][0] = zero4; acc[1][1] = zero4;
    {
#pragma unroll 4
        for (int ks = 0; ks < 16; ks++) {
            bshort8 a0 = *(const bshort8*)(buf + (l15) * 520 + ks * 32 + quad * 8);
            bshort8 a1b = *(const bshort8*)(buf + (16 + l15) * 520 + ks * 32 + quad * 8);
#pragma unroll
            for (int nt = 0; nt < 2; nt++) {
                bshort8 bfr = *(const bshort8*)(w2t + (((size_t)(w * 2 + nt) * 16 + ks) * 64 + lane) * 8);
                acc[0][nt] = __builtin_amdgcn_mfma_f32_16x16x32_bf16(a0, bfr, acc[0][nt], 0, 0, 0);
                acc[1][nt] = __builtin_amdgcn_mfma_f32_16x16x32_bf16(a1b, bfr, acc[1][nt], 0, 0, 0);
            }
        }
    }
    __syncthreads();

#pragma unroll
    for (int mt = 0; mt < 2; mt++) {
#pragma unroll
        for (int nt = 0; nt < 2; nt++) {
            int n0 = w * 32 + nt * 16;
            float bias = b2[n0 + l15];
#pragma unroll
            for (int r = 0; r < 4; r++) {
                int m = mt * 16 + quad * 4 + r;
                of32[m * 132 + n0 + l15] = res[mt][nt][r] + acc[mt][nt][r] + bias;
            }
        }
    }
    __syncthreads();

    {
        int c = t >> 1, half = t & 1, j0 = half * 16;
        float* dst = lout + ((size_t)(b * 128 + c)) * NSP + sp + j0;
#pragma unroll
        for (int i4 = 0; i4 < 4; i4++) {
            float4 ov = { of32[(j0 + i4 * 4 + 0) * 132 + c], of32[(j0 + i4 * 4 + 1) * 132 + c],
                          of32[(j0 + i4 * 4 + 2) * 132 + c], of32[(j0 + i4 * 4 + 3) * 132 + c] };
            *(float4*)(dst + i4 * 4) = ov;
        }
    }
}

extern "C" void kernel_launch(void* const* d_in, const int* in_sizes, int n_in,
                              void* d_out, int out_size, void* d_ws, size_t ws_size,
                              hipStream_t stream) {
    const float* x_in   = (const float*)d_in[0];
    const float* xg_in  = (const float*)d_in[1];
    const float* qkv_w  = (const float*)d_in[2];
    const float* qkv_b  = (const float*)d_in[3];
    const float* proj_w = (const float*)d_in[4];
    const float* proj_b = (const float*)d_in[5];
    const float* ln_g   = (const float*)d_in[6];
    const float* ln_b   = (const float*)d_in[7];
    const float* mlp_w1 = (const float*)d_in[8];
    const float* mlp_b1 = (const float*)d_in[9];
    const float* mlp_w2 = (const float*)d_in[10];
    const float* mlp_b2 = (const float*)d_in[11];
    const float* rq_w   = (const float*)d_in[12];
    const float* rq_b   = (const float*)d_in[13];
    const float* rk_w   = (const float*)d_in[14];
    const float* rk_b   = (const float*)d_in[15];
    const float* gqkv_w = (const float*)d_in[16];
    const float* gqkv_b = (const float*)d_in[17];
    const float* wo_w   = (const float*)d_in[18];
    const float* wo_b   = (const float*)d_in[19];
    const float* m2_w1  = (const float*)d_in[20];
    const float* m2_b1  = (const float*)d_in[21];
    const float* m2_w2  = (const float*)d_in[22];
    const float* m2_b2  = (const float*)d_in[23];

    float* out = (float*)d_out;
    float* ws  = (float*)d_ws;

    float* xg4 = ws;                                         // 524288
    float* xg  = ws + 524288;                                // 524288
    unsigned short* qgb  = (unsigned short*)(ws + 1048576);  // 524288 bf16
    unsigned short* kgb  = (unsigned short*)(ws + 1310720);  // 524288 bf16
    unsigned short* vgtb = (unsigned short*)(ws + 1572864);  // 524288 bf16 (V^T)
    float* og  = ws + 1835008;                               // 524288
    float* qh  = ws + 2359296;                               // 65536
    float* kh  = ws + 2424832;                               // 65536
    unsigned short* lnsc = (unsigned short*)(ws + 2492416);  // 6291456 bf16
    float* lpre = ws + 2492416 + 3145728;                    // 4194304
    unsigned short* wt   = (unsigned short*)(ws + 14026752); // 49152 bf16
    unsigned short* w1t  = (unsigned short*)(ws + 14051328); // 65536 bf16
    unsigned short* w2t  = (unsigned short*)(ws + 14084096); // 65536 bf16
    unsigned short* projt = (unsigned short*)(ws + 14116864); // 16384 bf16
    unsigned short* gw1t  = (unsigned short*)(ws + 14125056); // 65536 bf16
    unsigned short* gw2t  = (unsigned short*)(ws + 14157824); // 65536 bf16
    unsigned short* wot   = (unsigned short*)(ws + 14190592); // 16384 bf16
    unsigned short* qkvt  = (unsigned short*)(ws + 14198784); // 49152 bf16

    const size_t L_OUT = (size_t)BATCH * CDIM * NSP;
    float* gout = out + L_OUT;

    hipLaunchKernelGGL(k_prep_fat, dim3(2240), dim3(256), 0, stream,
                       gqkv_w, m2_w1, m2_w2, proj_w, mlp_w1, mlp_w2, wo_w, qkv_w,
                       wt, w1t, w2t, projt, gw1t, gw2t, wot, qkvt,
                       x_in, ln_g, ln_b, lnsc);
    hipLaunchKernelGGL(k_gqkv_mfma, dim3(256), dim3(256), 0, stream,
                       xg_in, qkvt, qkv_b, ln_g, ln_b, xg, qgb, kgb, vgtb);
    hipLaunchKernelGGL(k_gattn_mfma, dim3(2048), dim3(256), 0, stream, qgb, kgb, vgtb, og);
    hipLaunchKernelGGL(k_gmlp_mfma, dim3(256), dim3(256), 0, stream,
                       og, xg, projt, proj_b, ln_g, ln_b, gw1t, mlp_b1, gw2t, mlp_b2,
                       xg4, gout);
    hipLaunchKernelGGL(k_routing_qk, dim3(512), dim3(128), 0, stream,
                       xg4, rq_w, rq_b, rk_w, rk_b, qh, kh);
    hipLaunchKernelGGL(k_topk_gath, dim3(512), dim3(256), 0, stream,
                       qh, kh, xg4, ln_g, ln_b, lnsc);
    hipLaunchKernelGGL(k_local_wo_mfma, dim3(512), dim3(512), 0, stream,
                       lnsc, wt, gqkv_b, wot, wo_b, x_in, lpre);
    hipLaunchKernelGGL(k_mlp2_mfma, dim3(1024), dim3(256), 0, stream,
                       lpre, ln_g, ln_b, w1t, m2_b1, w2t, m2_b2, out);
}